// Round 14
// baseline (163.079 us; speedup 1.0000x reference)
//
#include <hip/hip_runtime.h>
#include <math.h>

typedef float f32x4 __attribute__((ext_vector_type(4)));

#define NCH 32   // scan chunks
#define CLN 32   // chunk length

// workspace float offsets
#define OFF_P   0          // [1024][512]
#define OFF_Q   524288     // [1024][512]
#define OFF_DTT 1048576    // [1024][2048]  dt tiles [tt][d]
#define OFF_SXT 3145728    // [1024][2048]  silu(conv(x)) tiles [d][tt]
#define OFF_BCT 5242880    // [1024][512]   B/C tiles [tt][k]
#define OFF_AN  5767168    // [1024][64]    normalized pool scalars a1[32],a2[32]
#define OFF_HIN 5832704    // [1024][512]   chunk-prefix h
#define OFF_WZ  6356992    // [2][192] z-gate consts
#define OFF_VEW 6357376    // [64]
#define OFF_AL2 6357440    // [2][512]
#define OFF_CNT 6358464    // [32] unsigned counters (memset to 0 each launch)

#define LOG2E 1.4426950408889634f
#define LN2   0.6931471805599453f

__device__ __forceinline__ float fexp2(float x){ return __builtin_amdgcn_exp2f(x); }
__device__ __forceinline__ float flog2(float x){ return __builtin_amdgcn_logf(x); }
__device__ __forceinline__ float frcp (float x){ return __builtin_amdgcn_rcpf(x); }
__device__ __forceinline__ float fsigmoid(float x){ return frcp(1.f + fexp2(-x*LOG2E)); }
__device__ __forceinline__ float fsilu(float x){ return x * fsigmoid(x); }
__device__ __forceinline__ float fsoftplus(float x){
  return fmaxf(x, 0.f) + LN2 * flog2(1.f + fexp2(-fabsf(x)*LOG2E));
}

__device__ __forceinline__ float wave_rsum(float v){
  #pragma unroll
  for (int o = 1; o < 64; o <<= 1) v += __shfl_xor(v, o, 64);
  return v;
}
__device__ __forceinline__ float wave_rmax(float v){
  #pragma unroll
  for (int o = 1; o < 64; o <<= 1) v = fmaxf(v, __shfl_xor(v, o, 64));
  return v;
}

// ---------------- shared scratch for projA ----------------
struct Smem {
  float a1[36], a2[36], a3[36];
  float xpt[20*65];     // padded stride 65
  float dtlr[32*4];
  float sxt[64*37];     // [d][ll] stride 37
  float dtt[32*64];     // [ll][d]
  float bct[32*16];     // [ll][k]
  float gw[64], gb[64], lnbs[64];
  float W[384];         // this branch's {W1,W2,W3}x128
  float cst[4];         // Av, Bq, Cq
};

__device__ __forceinline__ void consts_ln(float* gw, float* gb, float* lnbs, float* cst, int t,
    const float* pre_w, const float* pre_b, const float* ln_g, const float* ln_b){
  if (t < 64){
    float w = pre_w[t], b = pre_b[t];
    float mw = wave_rsum(w) * (1.f/64.f);
    float mb = wave_rsum(b) * (1.f/64.f);
    float wc = w - mw, bc = b - mb;
    float Av = wave_rsum(wc*wc) * (1.f/64.f);
    float Bq = wave_rsum(wc*bc) * (1.f/64.f);
    float Cq = wave_rsum(bc*bc) * (1.f/64.f);
    gw[t] = wc * ln_g[t];
    gb[t] = bc * ln_g[t];
    lnbs[t] = ln_b[t];
    if (t == 0){ cst[0] = Av; cst[1] = Bq; cst[2] = Cq; }
  }
}

// conv+silu+xproj+dt for one chunk; assumes S.a1/a2/a3 and S.W ready.
__device__ __forceinline__ void proj_body(
    Smem& S, int t,
    const float* __restrict__ cw, const float* __restrict__ cb,
    const float* __restrict__ xpw, const float* __restrict__ dw,
    const float* __restrict__ dbv){
  for (int i = t; i < 20*64; i += 512){
    int k = i >> 6, d = i & 63;
    S.xpt[k*65 + d] = xpw[i];
  }
  __syncthreads();
  {
    int d = t & 63, lq = t >> 6;
    float cw0=cw[d*4], cw1=cw[d*4+1], cw2=cw[d*4+2], cw3=cw[d*4+3];
    float cbd = cb[d];
    float W1d = S.W[d], W2d = S.W[128+d], W3d = S.W[256+d];
    #pragma unroll
    for (int j = 0; j < 4; ++j){
      int ll = lq*4 + j;
      float A1 = cw0*S.a1[ll] + cw1*S.a1[ll+1] + cw2*S.a1[ll+2] + cw3*S.a1[ll+3];
      float A2 = cw0*S.a2[ll] + cw1*S.a2[ll+1] + cw2*S.a2[ll+2] + cw3*S.a2[ll+3];
      float A3 = cw0*S.a3[ll] + cw1*S.a3[ll+1] + cw2*S.a3[ll+2] + cw3*S.a3[ll+3];
      float xc = W1d*A1 + W2d*A2 + W3d*A3 + cbd;
      S.sxt[d*37 + ll] = fsilu(xc);
    }
  }
  __syncthreads();
  {
    int ll = t >> 4, k = t & 15;
    float acc = 0.f;
    #pragma unroll 8
    for (int d = 0; d < 64; ++d) acc += S.xpt[(4+k)*65 + d] * S.sxt[d*37 + ll];
    S.bct[ll*16 + k] = acc;
  }
  if (t < 128){
    int ll = t >> 2, r = t & 3;
    float acc = 0.f;
    #pragma unroll 8
    for (int d = 0; d < 64; ++d) acc += S.xpt[r*65 + d] * S.sxt[d*37 + ll];
    S.dtlr[ll*4 + r] = acc;
  }
  __syncthreads();
  {
    int d = t & 63, lq = t >> 6;
    float w0=dw[d*4], w1=dw[d*4+1], w2=dw[d*4+2], w3=dw[d*4+3];
    float bd = dbv[d];
    #pragma unroll
    for (int j = 0; j < 4; ++j){
      int ll = lq*4 + j;
      float raw = bd + w0*S.dtlr[ll*4] + w1*S.dtlr[ll*4+1]
                     + w2*S.dtlr[ll*4+2] + w3*S.dtlr[ll*4+3];
      S.dtt[ll*64 + d] = fsoftplus(raw);
    }
  }
  __syncthreads();
}

// ---------------- K1: pool + consts + proj + persist + P,Q + folded prefix ----------------
__global__ void __launch_bounds__(512) k_projA(
    const float* __restrict__ img1, const float* __restrict__ img2,
    const float* pre_w, const float* pre_b, const float* ln_g, const float* ln_b,
    const float* in_w, const float* in_b_w, const float* A_log, const float* A_b_log,
    const float* conv_w, const float* conv_b, const float* convb_w, const float* convb_b,
    const float* xproj_w, const float* xprojb_w,
    const float* dt_w, const float* dt_b, const float* dtb_w, const float* dtb_b,
    const float* norm_w, const float* out_w, const float* post_w,
    float* __restrict__ ws){
  __shared__ __align__(16) Smem S;
  __shared__ unsigned s_last;
  int bi = blockIdx.x;                 // bq*32 + c
  int c = bi & 31, bq = bi >> 5, br = bq >> 4, b = bq & 15;
  int t = threadIdx.x;
  int wv = t >> 6, lane = t & 63;
  // ---- pool: each wave loads its rows (35 rows incl 3-row halo) ----
  const float* img = br ? img2 : img1;
  #pragma unroll
  for (int k = 0; k < 5; ++k){
    int i = wv + k*8;
    if (i < 35){
      bool valid = (c > 0) || (i >= 3);
      if (valid){
        int l = br ? (1026 - c*32 - i) : (c*32 - 3 + i);
        const f32x4* rp = (const f32x4*)(img + ((size_t)(b*1024 + l))*1024) + lane;
        f32x4 q0 = __builtin_nontemporal_load(rp +   0);
        f32x4 q1 = __builtin_nontemporal_load(rp +  64);
        f32x4 q2 = __builtin_nontemporal_load(rp + 128);
        f32x4 q3 = __builtin_nontemporal_load(rp + 192);
        float m = fmaxf(fmaxf(fmaxf(q0.x,q0.y), fmaxf(q0.z,q0.w)),
                        fmaxf(fmaxf(q1.x,q1.y), fmaxf(q1.z,q1.w)));
        m = fmaxf(m, fmaxf(fmaxf(fmaxf(q2.x,q2.y), fmaxf(q2.z,q2.w)),
                           fmaxf(fmaxf(q3.x,q3.y), fmaxf(q3.z,q3.w))));
        m = wave_rmax(m);
        if (lane == 0) S.a1[i] = m;
      } else if (lane == 0) S.a1[i] = 0.f;
    }
  }
  // ---- consts (overlap with load drain) ----
  consts_ln(S.gw, S.gb, S.lnbs, S.cst, t, pre_w, pre_b, ln_g, ln_b);
  __syncthreads();
  if (t < 128){
    const float* iw = br ? in_b_w : in_w;
    float s1 = 0.f, s2 = 0.f, s3 = 0.f;
    #pragma unroll 8
    for (int d = 0; d < 64; ++d){
      float w = iw[t*64 + d];
      s1 += w * S.gw[d]; s2 += w * S.gb[d]; s3 += w * S.lnbs[d];
    }
    S.W[      t] = s1;
    S.W[128 + t] = s2;
    S.W[256 + t] = s3;
  }
  float A2r = -fexp2((br ? A_b_log : A_log)[t] * LOG2E) * LOG2E;
  __syncthreads();
  // ---- convert raw max -> a1/a2/a3 ----
  if (t < 36){
    bool ok = (t < 35) && ((c > 0) || (t >= 3));
    float m = ok ? S.a1[t] : 0.f;
    float Av = S.cst[0], Bq = S.cst[1], Cq = S.cst[2];
    float inv = rsqrtf(m*m*Av + 2.f*m*Bq + Cq + 1e-5f);
    S.a1[t] = ok ? m*inv : 0.f;
    S.a2[t] = ok ? inv   : 0.f;
    S.a3[t] = ok ? 1.f   : 0.f;
  }
  proj_body(S, t,
            br ? convb_w : conv_w,  br ? convb_b : conv_b,
            br ? xprojb_w : xproj_w, br ? dtb_w : dt_w, br ? dtb_b : dt_b);
  // ---- persist tiles for scanY ----
  {
    int dd = t >> 3, tt0 = (t & 7)*4;
    f32x4 sv; sv.x = S.sxt[dd*37+tt0];   sv.y = S.sxt[dd*37+tt0+1];
              sv.z = S.sxt[dd*37+tt0+2]; sv.w = S.sxt[dd*37+tt0+3];
    *(f32x4*)(ws + OFF_SXT + (size_t)bi*2048 + dd*32 + tt0) = sv;
    f32x4 dv; dv.x = S.dtt[t*4];   dv.y = S.dtt[t*4+1];
              dv.z = S.dtt[t*4+2]; dv.w = S.dtt[t*4+3];
    *(f32x4*)(ws + OFF_DTT + (size_t)bi*2048 + t*4) = dv;
    if (t < 128){
      f32x4 bv; bv.x = S.bct[t*4];   bv.y = S.bct[t*4+1];
                bv.z = S.bct[t*4+2]; bv.w = S.bct[t*4+3];
      *(f32x4*)(ws + OFF_BCT + (size_t)bi*512 + t*4) = bv;
    }
    if (t < 32){
      ws[OFF_AN + (size_t)bi*64 + t]      = S.a1[t+3];
      ws[OFF_AN + (size_t)bi*64 + 32 + t] = S.a2[t+3];
    }
  }
  // ---- blocks 0 / 512 persist per-branch consts for scanY ----
  if (bi == 0 || bi == 512){
    ws[OFF_AL2 + br*512 + t] = A2r;
    if (t < 64){
      ws[OFF_WZ + br*192 +       t] = S.W[64 + t];
      ws[OFF_WZ + br*192 +  64 + t] = S.W[128 + 64 + t];
      ws[OFF_WZ + br*192 + 128 + t] = S.W[256 + 64 + t];
    }
    if (bi == 0 && t < 64){
      float s = 0.f;
      #pragma unroll 8
      for (int e = 0; e < 64; ++e) s += post_w[e] * out_w[e*64 + t];
      ws[OFF_VEW + t] = s * norm_w[t];
    }
  }
  // ---- per-chunk (P,Q) ----
  int d = wv*8 + (lane >> 3), n = lane & 7;
  float P = 1.f, Q = 0.f;
  #pragma unroll 4
  for (int tt = 0; tt < CLN; ++tt){
    float dtv = S.dtt[tt*64 + d];
    float xv  = S.sxt[d*37 + tt];
    float bv  = S.bct[tt*16 + n];
    float da  = fexp2(dtv * A2r);
    Q = fmaf(da, Q, dtv * bv * xv);
    P *= da;
  }
  ws[OFF_P + (size_t)bi*512 + t] = P;
  ws[OFF_Q + (size_t)bi*512 + t] = Q;
  // ---- folded scanB: last finisher per bq computes the chunk-prefix -> HIN ----
  __syncthreads();
  if (t == 0){
    __threadfence();   // release P,Q to agent scope
    unsigned* cnt = (unsigned*)(ws + OFF_CNT);
    unsigned old = __hip_atomic_fetch_add(&cnt[bq], 1u, __ATOMIC_ACQ_REL,
                                          __HIP_MEMORY_SCOPE_AGENT);
    s_last = (old == 31u) ? 1u : 0u;
  }
  __syncthreads();
  if (s_last){
    __threadfence();   // acquire: see other blocks' P,Q
    const float* Pp = ws + OFF_P + (size_t)bq*NCH*512 + t;
    const float* Qp = ws + OFF_Q + (size_t)bq*NCH*512 + t;
    float* Hp = ws + OFF_HIN + (size_t)bq*NCH*512 + t;
    float h = 0.f;
    #pragma unroll
    for (int base = 0; base < NCH; base += 8){
      float Pa[8], Qa[8];
      #pragma unroll
      for (int j = 0; j < 8; ++j){
        Pa[j] = Pp[(size_t)(base+j)*512];
        Qa[j] = Qp[(size_t)(base+j)*512];
      }
      #pragma unroll
      for (int j = 0; j < 8; ++j){
        Hp[(size_t)(base+j)*512] = h;
        h = fmaf(Pa[j], h, Qa[j]);
      }
    }
  }
}

// ---------------- K2: fwd+bwd pass-parallel replay + gate + epilogue ----------------
__global__ void __launch_bounds__(1024) k_scanY(
    const float* Dp, const float* Dp_b, const float* post_b,
    const float* __restrict__ ws, float* __restrict__ out){
  __shared__ __align__(16) struct {
    float dtt[2][2048];   // [team][tt*64+d]
    float sxt[2][2368];   // [team][d*37+tt] padded
    float bct[2][512];    // [team][tt*16+k]
    float an[2][64];
    float ylds[2][CLN*65];
  } C;
  int bi = blockIdx.x;                 // b*32 + oc (output tile)
  int oc = bi & 31, b = bi >> 5;
  int t = threadIdx.x;
  int team = t >> 9, u = t & 511;      // team 0 = fwd, team 1 = bwd
  int lane = t & 63;
  int wv_all = t >> 6;                 // 0..15
  int d = ((u >> 6) << 3) + ((u & 63) >> 3), n = u & 7;
  int ti = team ? ((b+16)*32 + (31 - oc)) : (b*32 + oc);
  // ---- issue loads (each team loads its own tile) ----
  f32x4 dv = *(const f32x4*)(ws + OFF_DTT + (size_t)ti*2048 + u*4);
  f32x4 sv = *(const f32x4*)(ws + OFF_SXT + (size_t)ti*2048 + u*4);
  float h   = ws[OFF_HIN + (size_t)ti*512 + u];
  float A2r = ws[OFF_AL2 + team*512 + u];
  float W1z = ws[OFF_WZ + team*192 +       d];
  float W2z = ws[OFF_WZ + team*192 +  64 + d];
  float W3z = ws[OFF_WZ + team*192 + 128 + d];
  float Dpd = (team ? Dp_b : Dp)[d];
  float ve  = ws[OFF_VEW + lane];
  float pb  = post_b[0];
  f32x4 bv4, av4;
  if (u < 128) bv4 = *(const f32x4*)(ws + OFF_BCT + (size_t)ti*512 + u*4);
  if (u < 16)  av4 = *(const f32x4*)(ws + OFF_AN  + (size_t)ti*64  + u*4);
  // ---- stage LDS ----
  {
    *(f32x4*)&C.dtt[team][u*4] = dv;
    int dd = u >> 3, tt0 = (u & 7)*4;
    C.sxt[team][dd*37+tt0+0] = sv.x; C.sxt[team][dd*37+tt0+1] = sv.y;
    C.sxt[team][dd*37+tt0+2] = sv.z; C.sxt[team][dd*37+tt0+3] = sv.w;
    if (u < 128) *(f32x4*)&C.bct[team][u*4] = bv4;
    if (u < 16)  *(f32x4*)&C.an[team][u*4]  = av4;
  }
  __syncthreads();
  // ---- replay + gate (both teams concurrent, separate ylds) ----
  {
    const float* dtt = C.dtt[team];
    const float* sxt = C.sxt[team];
    const float* bct = C.bct[team];
    const float* an  = C.an[team];
    float* yl = C.ylds[team];
    #pragma unroll 4
    for (int tt = 0; tt < CLN; ++tt){
      float dtv = dtt[tt*64 + d];
      float xv  = sxt[d*37 + tt];
      float bv  = bct[tt*16 + n];
      float cv  = bct[tt*16 + 8 + n];
      float da  = fexp2(dtv * A2r);
      h = fmaf(da, h, dtv * bv * xv);
      float pv = h * cv;
      pv += __shfl_xor(pv, 1, 64);
      pv += __shfl_xor(pv, 2, 64);
      pv += __shfl_xor(pv, 4, 64);
      if (n == 0){
        float y = pv + Dpd * xv;
        float zv = an[tt]*W1z + an[32+tt]*W2z + W3z;
        float g = fsilu(zv);
        int row = team ? (31 - tt) : tt;
        yl[row*65 + d] = y * g;
      }
    }
  }
  __syncthreads();
  // ---- epilogue: rmsnorm + collapsed matvec + sigmoid; 16 waves x 2 rows ----
  #pragma unroll
  for (int j = 0; j < 2; ++j){
    int row = wv_all*2 + j;
    float v = C.ylds[0][row*65 + lane] + C.ylds[1][row*65 + lane];
    float ss = v*v, dp = v*ve;
    #pragma unroll
    for (int o = 1; o < 64; o <<= 1){
      ss += __shfl_xor(ss, o, 64);
      dp += __shfl_xor(dp, o, 64);
    }
    if (lane == 0){
      float rstd = rsqrtf(ss*(1.f/64.f) + 1e-5f);
      out[b*1024 + oc*32 + row] = fsigmoid(dp*rstd + pb);
    }
  }
}

extern "C" void kernel_launch(void* const* d_in, const int* in_sizes, int n_in,
                              void* d_out, int out_size, void* d_ws, size_t ws_size,
                              hipStream_t stream){
  const float* img1      = (const float*)d_in[0];
  const float* img2      = (const float*)d_in[1];
  const float* pre_w     = (const float*)d_in[2];
  const float* pre_b     = (const float*)d_in[3];
  const float* ln_g      = (const float*)d_in[4];
  const float* ln_b      = (const float*)d_in[5];
  const float* in_w      = (const float*)d_in[6];
  const float* in_b_w    = (const float*)d_in[7];
  const float* conv_w    = (const float*)d_in[8];
  const float* conv_bias = (const float*)d_in[9];
  const float* convb_w   = (const float*)d_in[10];
  const float* convb_bias= (const float*)d_in[11];
  const float* xproj_w   = (const float*)d_in[12];
  const float* xprojb_w  = (const float*)d_in[13];
  const float* dt_w      = (const float*)d_in[14];
  const float* dt_bias   = (const float*)d_in[15];
  const float* dtb_w     = (const float*)d_in[16];
  const float* dtb_bias  = (const float*)d_in[17];
  const float* A_log     = (const float*)d_in[18];
  const float* A_b_log   = (const float*)d_in[19];
  const float* Dp        = (const float*)d_in[20];
  const float* Dp_b      = (const float*)d_in[21];
  const float* norm_w    = (const float*)d_in[22];
  const float* out_w     = (const float*)d_in[23];
  const float* post_w    = (const float*)d_in[24];
  const float* post_b    = (const float*)d_in[25];
  float* ws  = (float*)d_ws;
  float* out = (float*)d_out;

  hipMemsetAsync((void*)(ws + OFF_CNT), 0, NCH*sizeof(unsigned), stream);
  k_projA<<<1024, 512, 0, stream>>>(img1, img2, pre_w, pre_b, ln_g, ln_b,
                                    in_w, in_b_w, A_log, A_b_log,
                                    conv_w, conv_bias, convb_w, convb_bias,
                                    xproj_w, xprojb_w, dt_w, dt_bias, dtb_w, dtb_bias,
                                    norm_w, out_w, post_w, ws);
  k_scanY<<<512, 1024, 0, stream>>>(Dp, Dp_b, post_b, ws, out);
}

// Round 15
// 69.952 us; speedup vs baseline: 2.3313x; 2.3313x over previous
//
#include <hip/hip_runtime.h>
#include <math.h>

typedef float f32x4 __attribute__((ext_vector_type(4)));

#define NCH 32   // scan chunks
#define CLN 32   // chunk length

// workspace float offsets
#define OFF_P   0          // [1024][512]
#define OFF_Q   524288     // [1024][512]
#define OFF_DTT 1048576    // [1024][2048]  dt tiles [tt][d]
#define OFF_SXT 3145728    // [1024][2048]  silu(conv(x)) tiles [d][tt]
#define OFF_BCT 5242880    // [1024][512]   B/C tiles [tt][k]
#define OFF_AN  5767168    // [1024][64]    normalized pool scalars a1[32],a2[32]
#define OFF_HIN 5832704    // [1024][512]   chunk-prefix h
#define OFF_WZ  6356992    // [2][192] z-gate consts
#define OFF_VEW 6357376    // [64]
#define OFF_AL2 6357440    // [2][512]

#define LOG2E 1.4426950408889634f
#define LN2   0.6931471805599453f

__device__ __forceinline__ float fexp2(float x){ return __builtin_amdgcn_exp2f(x); }
__device__ __forceinline__ float flog2(float x){ return __builtin_amdgcn_logf(x); }
__device__ __forceinline__ float frcp (float x){ return __builtin_amdgcn_rcpf(x); }
__device__ __forceinline__ float fsigmoid(float x){ return frcp(1.f + fexp2(-x*LOG2E)); }
__device__ __forceinline__ float fsilu(float x){ return x * fsigmoid(x); }
__device__ __forceinline__ float fsoftplus(float x){
  return fmaxf(x, 0.f) + LN2 * flog2(1.f + fexp2(-fabsf(x)*LOG2E));
}

__device__ __forceinline__ float wave_rsum(float v){
  #pragma unroll
  for (int o = 1; o < 64; o <<= 1) v += __shfl_xor(v, o, 64);
  return v;
}
__device__ __forceinline__ float wave_rmax(float v){
  #pragma unroll
  for (int o = 1; o < 64; o <<= 1) v = fmaxf(v, __shfl_xor(v, o, 64));
  return v;
}

// ---------------- shared scratch for projA ----------------
struct Smem {
  float a1[36], a2[36], a3[36];
  float xpt[20*65];     // padded stride 65
  float dtlr[32*4];
  float sxt[64*37];     // [d][ll] stride 37
  float dtt[32*64];     // [ll][d]
  float bct[32*16];     // [ll][k]
  float gw[64], gb[64], lnbs[64];
  float W[384];         // this branch's {W1,W2,W3}x128
  float cst[4];         // Av, Bq, Cq
};

__device__ __forceinline__ void consts_ln(float* gw, float* gb, float* lnbs, float* cst, int t,
    const float* pre_w, const float* pre_b, const float* ln_g, const float* ln_b){
  if (t < 64){
    float w = pre_w[t], b = pre_b[t];
    float mw = wave_rsum(w) * (1.f/64.f);
    float mb = wave_rsum(b) * (1.f/64.f);
    float wc = w - mw, bc = b - mb;
    float Av = wave_rsum(wc*wc) * (1.f/64.f);
    float Bq = wave_rsum(wc*bc) * (1.f/64.f);
    float Cq = wave_rsum(bc*bc) * (1.f/64.f);
    gw[t] = wc * ln_g[t];
    gb[t] = bc * ln_g[t];
    lnbs[t] = ln_b[t];
    if (t == 0){ cst[0] = Av; cst[1] = Bq; cst[2] = Cq; }
  }
}

// conv+silu+xproj+dt for one chunk; assumes S.a1/a2/a3 and S.W ready.
__device__ __forceinline__ void proj_body(
    Smem& S, int t,
    const float* __restrict__ cw, const float* __restrict__ cb,
    const float* __restrict__ xpw, const float* __restrict__ dw,
    const float* __restrict__ dbv){
  for (int i = t; i < 20*64; i += 512){
    int k = i >> 6, d = i & 63;
    S.xpt[k*65 + d] = xpw[i];
  }
  __syncthreads();
  {
    int d = t & 63, lq = t >> 6;
    float cw0=cw[d*4], cw1=cw[d*4+1], cw2=cw[d*4+2], cw3=cw[d*4+3];
    float cbd = cb[d];
    float W1d = S.W[d], W2d = S.W[128+d], W3d = S.W[256+d];
    #pragma unroll
    for (int j = 0; j < 4; ++j){
      int ll = lq*4 + j;
      float A1 = cw0*S.a1[ll] + cw1*S.a1[ll+1] + cw2*S.a1[ll+2] + cw3*S.a1[ll+3];
      float A2 = cw0*S.a2[ll] + cw1*S.a2[ll+1] + cw2*S.a2[ll+2] + cw3*S.a2[ll+3];
      float A3 = cw0*S.a3[ll] + cw1*S.a3[ll+1] + cw2*S.a3[ll+2] + cw3*S.a3[ll+3];
      float xc = W1d*A1 + W2d*A2 + W3d*A3 + cbd;
      S.sxt[d*37 + ll] = fsilu(xc);
    }
  }
  __syncthreads();
  {
    int ll = t >> 4, k = t & 15;
    float acc = 0.f;
    #pragma unroll 8
    for (int d = 0; d < 64; ++d) acc += S.xpt[(4+k)*65 + d] * S.sxt[d*37 + ll];
    S.bct[ll*16 + k] = acc;
  }
  if (t < 128){
    int ll = t >> 2, r = t & 3;
    float acc = 0.f;
    #pragma unroll 8
    for (int d = 0; d < 64; ++d) acc += S.xpt[r*65 + d] * S.sxt[d*37 + ll];
    S.dtlr[ll*4 + r] = acc;
  }
  __syncthreads();
  {
    int d = t & 63, lq = t >> 6;
    float w0=dw[d*4], w1=dw[d*4+1], w2=dw[d*4+2], w3=dw[d*4+3];
    float bd = dbv[d];
    #pragma unroll
    for (int j = 0; j < 4; ++j){
      int ll = lq*4 + j;
      float raw = bd + w0*S.dtlr[ll*4] + w1*S.dtlr[ll*4+1]
                     + w2*S.dtlr[ll*4+2] + w3*S.dtlr[ll*4+3];
      S.dtt[ll*64 + d] = fsoftplus(raw);
    }
  }
  __syncthreads();
}

// ---------------- K1: fused pool + consts + proj + persist tiles + P,Q ----------------
__global__ void __launch_bounds__(512) k_projA(
    const float* __restrict__ img1, const float* __restrict__ img2,
    const float* pre_w, const float* pre_b, const float* ln_g, const float* ln_b,
    const float* in_w, const float* in_b_w, const float* A_log, const float* A_b_log,
    const float* conv_w, const float* conv_b, const float* convb_w, const float* convb_b,
    const float* xproj_w, const float* xprojb_w,
    const float* dt_w, const float* dt_b, const float* dtb_w, const float* dtb_b,
    const float* norm_w, const float* out_w, const float* post_w,
    float* __restrict__ ws){
  __shared__ __align__(16) Smem S;
  int bi = blockIdx.x;                 // bq*32 + c
  int c = bi & 31, bq = bi >> 5, br = bq >> 4, b = bq & 15;
  int t = threadIdx.x;
  int wv = t >> 6, lane = t & 63;
  // ---- pool: each wave loads its rows (35 rows incl 3-row halo) ----
  const float* img = br ? img2 : img1;
  #pragma unroll
  for (int k = 0; k < 5; ++k){
    int i = wv + k*8;
    if (i < 35){
      bool valid = (c > 0) || (i >= 3);
      if (valid){
        int l = br ? (1026 - c*32 - i) : (c*32 - 3 + i);
        const f32x4* rp = (const f32x4*)(img + ((size_t)(b*1024 + l))*1024) + lane;
        f32x4 q0 = __builtin_nontemporal_load(rp +   0);
        f32x4 q1 = __builtin_nontemporal_load(rp +  64);
        f32x4 q2 = __builtin_nontemporal_load(rp + 128);
        f32x4 q3 = __builtin_nontemporal_load(rp + 192);
        float m = fmaxf(fmaxf(fmaxf(q0.x,q0.y), fmaxf(q0.z,q0.w)),
                        fmaxf(fmaxf(q1.x,q1.y), fmaxf(q1.z,q1.w)));
        m = fmaxf(m, fmaxf(fmaxf(fmaxf(q2.x,q2.y), fmaxf(q2.z,q2.w)),
                           fmaxf(fmaxf(q3.x,q3.y), fmaxf(q3.z,q3.w))));
        m = wave_rmax(m);
        if (lane == 0) S.a1[i] = m;
      } else if (lane == 0) S.a1[i] = 0.f;
    }
  }
  // ---- consts (overlap with load drain) ----
  consts_ln(S.gw, S.gb, S.lnbs, S.cst, t, pre_w, pre_b, ln_g, ln_b);
  __syncthreads();
  if (t < 128){
    const float* iw = br ? in_b_w : in_w;
    float s1 = 0.f, s2 = 0.f, s3 = 0.f;
    #pragma unroll 8
    for (int d = 0; d < 64; ++d){
      float w = iw[t*64 + d];
      s1 += w * S.gw[d]; s2 += w * S.gb[d]; s3 += w * S.lnbs[d];
    }
    S.W[      t] = s1;
    S.W[128 + t] = s2;
    S.W[256 + t] = s3;
  }
  float A2r = -fexp2((br ? A_b_log : A_log)[t] * LOG2E) * LOG2E;
  __syncthreads();
  // ---- convert raw max -> a1/a2/a3 ----
  if (t < 36){
    bool ok = (t < 35) && ((c > 0) || (t >= 3));
    float m = ok ? S.a1[t] : 0.f;
    float Av = S.cst[0], Bq = S.cst[1], Cq = S.cst[2];
    float inv = rsqrtf(m*m*Av + 2.f*m*Bq + Cq + 1e-5f);
    S.a1[t] = ok ? m*inv : 0.f;
    S.a2[t] = ok ? inv   : 0.f;
    S.a3[t] = ok ? 1.f   : 0.f;
  }
  proj_body(S, t,
            br ? convb_w : conv_w,  br ? convb_b : conv_b,
            br ? xprojb_w : xproj_w, br ? dtb_w : dt_w, br ? dtb_b : dt_b);
  // ---- persist tiles for scanY ----
  {
    int dd = t >> 3, tt0 = (t & 7)*4;
    f32x4 sv; sv.x = S.sxt[dd*37+tt0];   sv.y = S.sxt[dd*37+tt0+1];
              sv.z = S.sxt[dd*37+tt0+2]; sv.w = S.sxt[dd*37+tt0+3];
    *(f32x4*)(ws + OFF_SXT + (size_t)bi*2048 + dd*32 + tt0) = sv;
    f32x4 dv; dv.x = S.dtt[t*4];   dv.y = S.dtt[t*4+1];
              dv.z = S.dtt[t*4+2]; dv.w = S.dtt[t*4+3];
    *(f32x4*)(ws + OFF_DTT + (size_t)bi*2048 + t*4) = dv;
    if (t < 128){
      f32x4 bv; bv.x = S.bct[t*4];   bv.y = S.bct[t*4+1];
                bv.z = S.bct[t*4+2]; bv.w = S.bct[t*4+3];
      *(f32x4*)(ws + OFF_BCT + (size_t)bi*512 + t*4) = bv;
    }
    if (t < 32){
      ws[OFF_AN + (size_t)bi*64 + t]      = S.a1[t+3];
      ws[OFF_AN + (size_t)bi*64 + 32 + t] = S.a2[t+3];
    }
  }
  // ---- blocks 0 / 512 persist per-branch consts for scanY ----
  if (bi == 0 || bi == 512){
    ws[OFF_AL2 + br*512 + t] = A2r;
    if (t < 64){
      ws[OFF_WZ + br*192 +       t] = S.W[64 + t];
      ws[OFF_WZ + br*192 +  64 + t] = S.W[128 + 64 + t];
      ws[OFF_WZ + br*192 + 128 + t] = S.W[256 + 64 + t];
    }
    if (bi == 0 && t < 64){
      float s = 0.f;
      #pragma unroll 8
      for (int e = 0; e < 64; ++e) s += post_w[e] * out_w[e*64 + t];
      ws[OFF_VEW + t] = s * norm_w[t];
    }
  }
  // ---- per-chunk (P,Q) ----
  int d = wv*8 + (lane >> 3), n = lane & 7;
  float P = 1.f, Q = 0.f;
  #pragma unroll 4
  for (int tt = 0; tt < CLN; ++tt){
    float dtv = S.dtt[tt*64 + d];
    float xv  = S.sxt[d*37 + tt];
    float bv  = S.bct[tt*16 + n];
    float da  = fexp2(dtv * A2r);
    Q = fmaf(da, Q, dtv * bv * xv);
    P *= da;
  }
  ws[OFF_P + (size_t)bi*512 + t] = P;
  ws[OFF_Q + (size_t)bi*512 + t] = Q;
}

// ---------------- K2: combine chunk summaries once -> HIN ----------------
__global__ void __launch_bounds__(64) k_scanB(float* __restrict__ ws){
  int gid = blockIdx.x*64 + threadIdx.x;   // 0..16383
  int bq = gid >> 9, dn = gid & 511;
  size_t base = (size_t)bq*NCH*512 + dn;
  float P[NCH], Q[NCH];
  #pragma unroll
  for (int c = 0; c < NCH; ++c){
    P[c] = ws[OFF_P + base + (size_t)c*512];
    Q[c] = ws[OFF_Q + base + (size_t)c*512];
  }
  float h = 0.f;
  #pragma unroll
  for (int c = 0; c < NCH; ++c){
    ws[OFF_HIN + base + (size_t)c*512] = h;
    h = fmaf(P[c], h, Q[c]);
  }
}

// ---------------- K3: fwd+bwd pass-parallel replay + gate + epilogue ----------------
__global__ void __launch_bounds__(1024) k_scanY(
    const float* Dp, const float* Dp_b, const float* post_b,
    const float* __restrict__ ws, float* __restrict__ out){
  __shared__ __align__(16) struct {
    float dtt[2][2048];   // [team][tt*64+d]
    float sxt[2][2368];   // [team][d*37+tt] padded
    float bct[2][512];    // [team][tt*16+k]
    float an[2][64];
    float ylds[2][CLN*65];
  } C;
  int bi = blockIdx.x;                 // b*32 + oc (output tile)
  int oc = bi & 31, b = bi >> 5;
  int t = threadIdx.x;
  int team = t >> 9, u = t & 511;      // team 0 = fwd, team 1 = bwd
  int lane = t & 63;
  int wv_all = t >> 6;                 // 0..15
  int d = ((u >> 6) << 3) + ((u & 63) >> 3), n = u & 7;
  int ti = team ? ((b+16)*32 + (31 - oc)) : (b*32 + oc);
  // ---- issue loads (each team loads its own tile) ----
  f32x4 dv = *(const f32x4*)(ws + OFF_DTT + (size_t)ti*2048 + u*4);
  f32x4 sv = *(const f32x4*)(ws + OFF_SXT + (size_t)ti*2048 + u*4);
  float h   = ws[OFF_HIN + (size_t)ti*512 + u];
  float A2r = ws[OFF_AL2 + team*512 + u];
  float W1z = ws[OFF_WZ + team*192 +       d];
  float W2z = ws[OFF_WZ + team*192 +  64 + d];
  float W3z = ws[OFF_WZ + team*192 + 128 + d];
  float Dpd = (team ? Dp_b : Dp)[d];
  float ve  = ws[OFF_VEW + lane];
  float pb  = post_b[0];
  f32x4 bv4, av4;
  if (u < 128) bv4 = *(const f32x4*)(ws + OFF_BCT + (size_t)ti*512 + u*4);
  if (u < 16)  av4 = *(const f32x4*)(ws + OFF_AN  + (size_t)ti*64  + u*4);
  // ---- stage LDS ----
  {
    *(f32x4*)&C.dtt[team][u*4] = dv;
    int dd = u >> 3, tt0 = (u & 7)*4;
    C.sxt[team][dd*37+tt0+0] = sv.x; C.sxt[team][dd*37+tt0+1] = sv.y;
    C.sxt[team][dd*37+tt0+2] = sv.z; C.sxt[team][dd*37+tt0+3] = sv.w;
    if (u < 128) *(f32x4*)&C.bct[team][u*4] = bv4;
    if (u < 16)  *(f32x4*)&C.an[team][u*4]  = av4;
  }
  __syncthreads();
  // ---- replay + gate (both teams concurrent, separate ylds) ----
  {
    const float* dtt = C.dtt[team];
    const float* sxt = C.sxt[team];
    const float* bct = C.bct[team];
    const float* an  = C.an[team];
    float* yl = C.ylds[team];
    #pragma unroll 4
    for (int tt = 0; tt < CLN; ++tt){
      float dtv = dtt[tt*64 + d];
      float xv  = sxt[d*37 + tt];
      float bv  = bct[tt*16 + n];
      float cv  = bct[tt*16 + 8 + n];
      float da  = fexp2(dtv * A2r);
      h = fmaf(da, h, dtv * bv * xv);
      float pv = h * cv;
      pv += __shfl_xor(pv, 1, 64);
      pv += __shfl_xor(pv, 2, 64);
      pv += __shfl_xor(pv, 4, 64);
      if (n == 0){
        float y = pv + Dpd * xv;
        float zv = an[tt]*W1z + an[32+tt]*W2z + W3z;
        float g = fsilu(zv);
        int row = team ? (31 - tt) : tt;
        yl[row*65 + d] = y * g;
      }
    }
  }
  __syncthreads();
  // ---- epilogue: rmsnorm + collapsed matvec + sigmoid; 16 waves x 2 rows ----
  #pragma unroll
  for (int j = 0; j < 2; ++j){
    int row = wv_all*2 + j;
    float v = C.ylds[0][row*65 + lane] + C.ylds[1][row*65 + lane];
    float ss = v*v, dp = v*ve;
    #pragma unroll
    for (int o = 1; o < 64; o <<= 1){
      ss += __shfl_xor(ss, o, 64);
      dp += __shfl_xor(dp, o, 64);
    }
    if (lane == 0){
      float rstd = rsqrtf(ss*(1.f/64.f) + 1e-5f);
      out[b*1024 + oc*32 + row] = fsigmoid(dp*rstd + pb);
    }
  }
}

extern "C" void kernel_launch(void* const* d_in, const int* in_sizes, int n_in,
                              void* d_out, int out_size, void* d_ws, size_t ws_size,
                              hipStream_t stream){
  const float* img1      = (const float*)d_in[0];
  const float* img2      = (const float*)d_in[1];
  const float* pre_w     = (const float*)d_in[2];
  const float* pre_b     = (const float*)d_in[3];
  const float* ln_g      = (const float*)d_in[4];
  const float* ln_b      = (const float*)d_in[5];
  const float* in_w      = (const float*)d_in[6];
  const float* in_b_w    = (const float*)d_in[7];
  const float* conv_w    = (const float*)d_in[8];
  const float* conv_bias = (const float*)d_in[9];
  const float* convb_w   = (const float*)d_in[10];
  const float* convb_bias= (const float*)d_in[11];
  const float* xproj_w   = (const float*)d_in[12];
  const float* xprojb_w  = (const float*)d_in[13];
  const float* dt_w      = (const float*)d_in[14];
  const float* dt_bias   = (const float*)d_in[15];
  const float* dtb_w     = (const float*)d_in[16];
  const float* dtb_bias  = (const float*)d_in[17];
  const float* A_log     = (const float*)d_in[18];
  const float* A_b_log   = (const float*)d_in[19];
  const float* Dp        = (const float*)d_in[20];
  const float* Dp_b      = (const float*)d_in[21];
  const float* norm_w    = (const float*)d_in[22];
  const float* out_w     = (const float*)d_in[23];
  const float* post_w    = (const float*)d_in[24];
  const float* post_b    = (const float*)d_in[25];
  float* ws  = (float*)d_ws;
  float* out = (float*)d_out;

  k_projA<<<1024, 512, 0, stream>>>(img1, img2, pre_w, pre_b, ln_g, ln_b,
                                    in_w, in_b_w, A_log, A_b_log,
                                    conv_w, conv_bias, convb_w, convb_bias,
                                    xproj_w, xprojb_w, dt_w, dt_bias, dtb_w, dtb_bias,
                                    norm_w, out_w, post_w, ws);
  k_scanB<<<256, 64, 0, stream>>>(ws);
  k_scanY<<<512, 1024, 0, stream>>>(Dp, Dp_b, post_b, ws, out);
}

// Round 16
// 68.875 us; speedup vs baseline: 2.3677x; 1.0156x over previous
//
#include <hip/hip_runtime.h>
#include <math.h>

typedef float    f32x4 __attribute__((ext_vector_type(4)));
typedef _Float16 f16x4 __attribute__((ext_vector_type(4)));

#define NCH 32   // scan chunks
#define CLN 32   // chunk length

// workspace float offsets
#define OFF_P     0          // [1024][512] f32
#define OFF_Q     524288     // [1024][512] f32
#define OFF_HIN   1048576    // [1024][512] f32
#define OFF_AN    1572864    // [1024][64]  f32  a1[32],a2[32]
#define OFF_WZ    1638400    // [2][192] f32
#define OFF_VEW   1638784    // [64] f32
#define OFF_AL2   1638848    // [2][512] f32
#define OFF_TILEH 1640448    // half-array base (16B aligned)
// half offsets (units of _Float16) relative to OFF_TILEH base:
#define DTT_H 0              // [1024][2048]
#define SXT_H 2097152        // [1024][2048]
#define BCT_H 4194304        // [1024][512]

#define LOG2E 1.4426950408889634f
#define LN2   0.6931471805599453f

__device__ __forceinline__ float fexp2(float x){ return __builtin_amdgcn_exp2f(x); }
__device__ __forceinline__ float flog2(float x){ return __builtin_amdgcn_logf(x); }
__device__ __forceinline__ float frcp (float x){ return __builtin_amdgcn_rcpf(x); }
__device__ __forceinline__ float fsigmoid(float x){ return frcp(1.f + fexp2(-x*LOG2E)); }
__device__ __forceinline__ float fsilu(float x){ return x * fsigmoid(x); }
__device__ __forceinline__ float fsoftplus(float x){
  return fmaxf(x, 0.f) + LN2 * flog2(1.f + fexp2(-fabsf(x)*LOG2E));
}

__device__ __forceinline__ float wave_rsum(float v){
  #pragma unroll
  for (int o = 1; o < 64; o <<= 1) v += __shfl_xor(v, o, 64);
  return v;
}
__device__ __forceinline__ float wave_rmax(float v){
  #pragma unroll
  for (int o = 1; o < 64; o <<= 1) v = fmaxf(v, __shfl_xor(v, o, 64));
  return v;
}

// ---------------- shared scratch for projA ----------------
struct Smem {
  float a1[36], a2[36], a3[36];
  float xpt[20*65];     // padded stride 65
  float dtlr[32*4];
  float sxt[64*37];     // [d][ll] stride 37
  float dtt[32*64];     // [ll][d]
  float bct[32*16];     // [ll][k]
  float gw[64], gb[64], lnbs[64];
  float W[384];         // this branch's {W1,W2,W3}x128
  float cst[4];         // Av, Bq, Cq
};

__device__ __forceinline__ void consts_ln(float* gw, float* gb, float* lnbs, float* cst, int t,
    const float* pre_w, const float* pre_b, const float* ln_g, const float* ln_b){
  if (t < 64){
    float w = pre_w[t], b = pre_b[t];
    float mw = wave_rsum(w) * (1.f/64.f);
    float mb = wave_rsum(b) * (1.f/64.f);
    float wc = w - mw, bc = b - mb;
    float Av = wave_rsum(wc*wc) * (1.f/64.f);
    float Bq = wave_rsum(wc*bc) * (1.f/64.f);
    float Cq = wave_rsum(bc*bc) * (1.f/64.f);
    gw[t] = wc * ln_g[t];
    gb[t] = bc * ln_g[t];
    lnbs[t] = ln_b[t];
    if (t == 0){ cst[0] = Av; cst[1] = Bq; cst[2] = Cq; }
  }
}

// conv+silu+xproj+dt for one chunk; assumes S.a1/a2/a3 and S.W ready.
__device__ __forceinline__ void proj_body(
    Smem& S, int t,
    const float* __restrict__ cw, const float* __restrict__ cb,
    const float* __restrict__ xpw, const float* __restrict__ dw,
    const float* __restrict__ dbv){
  for (int i = t; i < 20*64; i += 512){
    int k = i >> 6, d = i & 63;
    S.xpt[k*65 + d] = xpw[i];
  }
  __syncthreads();
  {
    int d = t & 63, lq = t >> 6;
    float cw0=cw[d*4], cw1=cw[d*4+1], cw2=cw[d*4+2], cw3=cw[d*4+3];
    float cbd = cb[d];
    float W1d = S.W[d], W2d = S.W[128+d], W3d = S.W[256+d];
    #pragma unroll
    for (int j = 0; j < 4; ++j){
      int ll = lq*4 + j;
      float A1 = cw0*S.a1[ll] + cw1*S.a1[ll+1] + cw2*S.a1[ll+2] + cw3*S.a1[ll+3];
      float A2 = cw0*S.a2[ll] + cw1*S.a2[ll+1] + cw2*S.a2[ll+2] + cw3*S.a2[ll+3];
      float A3 = cw0*S.a3[ll] + cw1*S.a3[ll+1] + cw2*S.a3[ll+2] + cw3*S.a3[ll+3];
      float xc = W1d*A1 + W2d*A2 + W3d*A3 + cbd;
      S.sxt[d*37 + ll] = fsilu(xc);
    }
  }
  __syncthreads();
  {
    int ll = t >> 4, k = t & 15;
    float acc = 0.f;
    #pragma unroll 8
    for (int d = 0; d < 64; ++d) acc += S.xpt[(4+k)*65 + d] * S.sxt[d*37 + ll];
    S.bct[ll*16 + k] = acc;
  }
  if (t < 128){
    int ll = t >> 2, r = t & 3;
    float acc = 0.f;
    #pragma unroll 8
    for (int d = 0; d < 64; ++d) acc += S.xpt[r*65 + d] * S.sxt[d*37 + ll];
    S.dtlr[ll*4 + r] = acc;
  }
  __syncthreads();
  {
    int d = t & 63, lq = t >> 6;
    float w0=dw[d*4], w1=dw[d*4+1], w2=dw[d*4+2], w3=dw[d*4+3];
    float bd = dbv[d];
    #pragma unroll
    for (int j = 0; j < 4; ++j){
      int ll = lq*4 + j;
      float raw = bd + w0*S.dtlr[ll*4] + w1*S.dtlr[ll*4+1]
                     + w2*S.dtlr[ll*4+2] + w3*S.dtlr[ll*4+3];
      S.dtt[ll*64 + d] = fsoftplus(raw);
    }
  }
  __syncthreads();
}

// ---------------- K1: fused pool + consts + proj + persist fp16 tiles + P,Q ----------------
__global__ void __launch_bounds__(512) k_projA(
    const float* __restrict__ img1, const float* __restrict__ img2,
    const float* pre_w, const float* pre_b, const float* ln_g, const float* ln_b,
    const float* in_w, const float* in_b_w, const float* A_log, const float* A_b_log,
    const float* conv_w, const float* conv_b, const float* convb_w, const float* convb_b,
    const float* xproj_w, const float* xprojb_w,
    const float* dt_w, const float* dt_b, const float* dtb_w, const float* dtb_b,
    const float* norm_w, const float* out_w, const float* post_w,
    float* __restrict__ ws){
  __shared__ __align__(16) Smem S;
  int bi = blockIdx.x;                 // bq*32 + c
  int c = bi & 31, bq = bi >> 5, br = bq >> 4, b = bq & 15;
  int t = threadIdx.x;
  int wv = t >> 6, lane = t & 63;
  // ---- pool: each wave loads its rows (35 rows incl 3-row halo) ----
  const float* img = br ? img2 : img1;
  #pragma unroll
  for (int k = 0; k < 5; ++k){
    int i = wv + k*8;
    if (i < 35){
      bool valid = (c > 0) || (i >= 3);
      if (valid){
        int l = br ? (1026 - c*32 - i) : (c*32 - 3 + i);
        const f32x4* rp = (const f32x4*)(img + ((size_t)(b*1024 + l))*1024) + lane;
        f32x4 q0 = __builtin_nontemporal_load(rp +   0);
        f32x4 q1 = __builtin_nontemporal_load(rp +  64);
        f32x4 q2 = __builtin_nontemporal_load(rp + 128);
        f32x4 q3 = __builtin_nontemporal_load(rp + 192);
        float m = fmaxf(fmaxf(fmaxf(q0.x,q0.y), fmaxf(q0.z,q0.w)),
                        fmaxf(fmaxf(q1.x,q1.y), fmaxf(q1.z,q1.w)));
        m = fmaxf(m, fmaxf(fmaxf(fmaxf(q2.x,q2.y), fmaxf(q2.z,q2.w)),
                           fmaxf(fmaxf(q3.x,q3.y), fmaxf(q3.z,q3.w))));
        m = wave_rmax(m);
        if (lane == 0) S.a1[i] = m;
      } else if (lane == 0) S.a1[i] = 0.f;
    }
  }
  // ---- consts (overlap with load drain) ----
  consts_ln(S.gw, S.gb, S.lnbs, S.cst, t, pre_w, pre_b, ln_g, ln_b);
  __syncthreads();
  if (t < 128){
    const float* iw = br ? in_b_w : in_w;
    float s1 = 0.f, s2 = 0.f, s3 = 0.f;
    #pragma unroll 8
    for (int d = 0; d < 64; ++d){
      float w = iw[t*64 + d];
      s1 += w * S.gw[d]; s2 += w * S.gb[d]; s3 += w * S.lnbs[d];
    }
    S.W[      t] = s1;
    S.W[128 + t] = s2;
    S.W[256 + t] = s3;
  }
  float A2r = -fexp2((br ? A_b_log : A_log)[t] * LOG2E) * LOG2E;
  __syncthreads();
  // ---- convert raw max -> a1/a2/a3 ----
  if (t < 36){
    bool ok = (t < 35) && ((c > 0) || (t >= 3));
    float m = ok ? S.a1[t] : 0.f;
    float Av = S.cst[0], Bq = S.cst[1], Cq = S.cst[2];
    float inv = rsqrtf(m*m*Av + 2.f*m*Bq + Cq + 1e-5f);
    S.a1[t] = ok ? m*inv : 0.f;
    S.a2[t] = ok ? inv   : 0.f;
    S.a3[t] = ok ? 1.f   : 0.f;
  }
  proj_body(S, t,
            br ? convb_w : conv_w,  br ? convb_b : conv_b,
            br ? xprojb_w : xproj_w, br ? dtb_w : dt_w, br ? dtb_b : dt_b);
  // ---- persist tiles (fp16) for scanY ----
  {
    _Float16* th = (_Float16*)(ws + OFF_TILEH);
    int dd = t >> 3, tt0 = (t & 7)*4;
    f32x4 sv; sv.x = S.sxt[dd*37+tt0];   sv.y = S.sxt[dd*37+tt0+1];
              sv.z = S.sxt[dd*37+tt0+2]; sv.w = S.sxt[dd*37+tt0+3];
    *(f16x4*)(th + SXT_H + (size_t)bi*2048 + dd*32 + tt0) =
        __builtin_convertvector(sv, f16x4);
    f32x4 dv; dv.x = S.dtt[t*4];   dv.y = S.dtt[t*4+1];
              dv.z = S.dtt[t*4+2]; dv.w = S.dtt[t*4+3];
    *(f16x4*)(th + DTT_H + (size_t)bi*2048 + t*4) =
        __builtin_convertvector(dv, f16x4);
    if (t < 128){
      f32x4 bv; bv.x = S.bct[t*4];   bv.y = S.bct[t*4+1];
                bv.z = S.bct[t*4+2]; bv.w = S.bct[t*4+3];
      *(f16x4*)(th + BCT_H + (size_t)bi*512 + t*4) =
          __builtin_convertvector(bv, f16x4);
    }
    if (t < 32){
      ws[OFF_AN + (size_t)bi*64 + t]      = S.a1[t+3];
      ws[OFF_AN + (size_t)bi*64 + 32 + t] = S.a2[t+3];
    }
  }
  // ---- blocks 0 / 512 persist per-branch consts for scanY ----
  if (bi == 0 || bi == 512){
    ws[OFF_AL2 + br*512 + t] = A2r;
    if (t < 64){
      ws[OFF_WZ + br*192 +       t] = S.W[64 + t];
      ws[OFF_WZ + br*192 +  64 + t] = S.W[128 + 64 + t];
      ws[OFF_WZ + br*192 + 128 + t] = S.W[256 + 64 + t];
    }
    if (bi == 0 && t < 64){
      float s = 0.f;
      #pragma unroll 8
      for (int e = 0; e < 64; ++e) s += post_w[e] * out_w[e*64 + t];
      ws[OFF_VEW + t] = s * norm_w[t];
    }
  }
  // ---- per-chunk (P,Q) ----
  int d = wv*8 + (lane >> 3), n = lane & 7;
  float P = 1.f, Q = 0.f;
  #pragma unroll 4
  for (int tt = 0; tt < CLN; ++tt){
    float dtv = S.dtt[tt*64 + d];
    float xv  = S.sxt[d*37 + tt];
    float bv  = S.bct[tt*16 + n];
    float da  = fexp2(dtv * A2r);
    Q = fmaf(da, Q, dtv * bv * xv);
    P *= da;
  }
  ws[OFF_P + (size_t)bi*512 + t] = P;
  ws[OFF_Q + (size_t)bi*512 + t] = Q;
}

// ---------------- K2: combine chunk summaries once -> HIN ----------------
__global__ void __launch_bounds__(256) k_scanB(float* __restrict__ ws){
  int gid = blockIdx.x*256 + threadIdx.x;   // 0..16383
  int bq = gid >> 9, dn = gid & 511;
  size_t base = (size_t)bq*NCH*512 + dn;
  float P[NCH], Q[NCH];
  #pragma unroll
  for (int c = 0; c < NCH; ++c){
    P[c] = ws[OFF_P + base + (size_t)c*512];
    Q[c] = ws[OFF_Q + base + (size_t)c*512];
  }
  float h = 0.f;
  #pragma unroll
  for (int c = 0; c < NCH; ++c){
    ws[OFF_HIN + base + (size_t)c*512] = h;
    h = fmaf(P[c], h, Q[c]);
  }
}

// ---------------- K3: fwd+bwd pass-parallel replay + gate + epilogue ----------------
__global__ void __launch_bounds__(1024) k_scanY(
    const float* Dp, const float* Dp_b, const float* post_b,
    const float* __restrict__ ws, float* __restrict__ out){
  __shared__ __align__(16) struct {
    float dtt[2][2048];   // [team][tt*64+d]
    float sxt[2][2368];   // [team][d*37+tt] padded
    float bct[2][512];    // [team][tt*16+k]
    float an[2][64];
    float ylds[2][CLN*65];
  } C;
  int bi = blockIdx.x;                 // b*32 + oc (output tile)
  int oc = bi & 31, b = bi >> 5;
  int t = threadIdx.x;
  int team = t >> 9, u = t & 511;      // team 0 = fwd, team 1 = bwd
  int lane = t & 63;
  int wv_all = t >> 6;                 // 0..15
  int d = ((u >> 6) << 3) + ((u & 63) >> 3), n = u & 7;
  int ti = team ? ((b+16)*32 + (31 - oc)) : (b*32 + oc);
  const _Float16* th = (const _Float16*)(ws + OFF_TILEH);
  // ---- issue loads (each team loads its own tile; fp16 tiles) ----
  f16x4 dvh = *(const f16x4*)(th + DTT_H + (size_t)ti*2048 + u*4);
  f16x4 svh = *(const f16x4*)(th + SXT_H + (size_t)ti*2048 + u*4);
  float h   = ws[OFF_HIN + (size_t)ti*512 + u];
  float A2r = ws[OFF_AL2 + team*512 + u];
  float W1z = ws[OFF_WZ + team*192 +       d];
  float W2z = ws[OFF_WZ + team*192 +  64 + d];
  float W3z = ws[OFF_WZ + team*192 + 128 + d];
  float Dpd = (team ? Dp_b : Dp)[d];
  float ve  = ws[OFF_VEW + lane];
  float pb  = post_b[0];
  f16x4 bvh;
  f32x4 av4;
  if (u < 128) bvh = *(const f16x4*)(th + BCT_H + (size_t)ti*512 + u*4);
  if (u < 16)  av4 = *(const f32x4*)(ws + OFF_AN + (size_t)ti*64 + u*4);
  // ---- stage LDS (converted to f32) ----
  {
    f32x4 dv = __builtin_convertvector(dvh, f32x4);
    f32x4 sv = __builtin_convertvector(svh, f32x4);
    *(f32x4*)&C.dtt[team][u*4] = dv;
    int dd = u >> 3, tt0 = (u & 7)*4;
    C.sxt[team][dd*37+tt0+0] = sv.x; C.sxt[team][dd*37+tt0+1] = sv.y;
    C.sxt[team][dd*37+tt0+2] = sv.z; C.sxt[team][dd*37+tt0+3] = sv.w;
    if (u < 128){
      f32x4 bv = __builtin_convertvector(bvh, f32x4);
      *(f32x4*)&C.bct[team][u*4] = bv;
    }
    if (u < 16)  *(f32x4*)&C.an[team][u*4]  = av4;
  }
  __syncthreads();
  // ---- replay + gate (both teams concurrent, separate ylds) ----
  {
    const float* dtt = C.dtt[team];
    const float* sxt = C.sxt[team];
    const float* bct = C.bct[team];
    const float* an  = C.an[team];
    float* yl = C.ylds[team];
    #pragma unroll 4
    for (int tt = 0; tt < CLN; ++tt){
      float dtv = dtt[tt*64 + d];
      float xv  = sxt[d*37 + tt];
      float bv  = bct[tt*16 + n];
      float cv  = bct[tt*16 + 8 + n];
      float da  = fexp2(dtv * A2r);
      h = fmaf(da, h, dtv * bv * xv);
      float pv = h * cv;
      pv += __shfl_xor(pv, 1, 64);
      pv += __shfl_xor(pv, 2, 64);
      pv += __shfl_xor(pv, 4, 64);
      if (n == 0){
        float y = pv + Dpd * xv;
        float zv = an[tt]*W1z + an[32+tt]*W2z + W3z;
        float g = fsilu(zv);
        int row = team ? (31 - tt) : tt;
        yl[row*65 + d] = y * g;
      }
    }
  }
  __syncthreads();
  // ---- epilogue: rmsnorm + collapsed matvec + sigmoid; 16 waves x 2 rows ----
  #pragma unroll
  for (int j = 0; j < 2; ++j){
    int row = wv_all*2 + j;
    float v = C.ylds[0][row*65 + lane] + C.ylds[1][row*65 + lane];
    float ss = v*v, dp = v*ve;
    #pragma unroll
    for (int o = 1; o < 64; o <<= 1){
      ss += __shfl_xor(ss, o, 64);
      dp += __shfl_xor(dp, o, 64);
    }
    if (lane == 0){
      float rstd = rsqrtf(ss*(1.f/64.f) + 1e-5f);
      out[b*1024 + oc*32 + row] = fsigmoid(dp*rstd + pb);
    }
  }
}

extern "C" void kernel_launch(void* const* d_in, const int* in_sizes, int n_in,
                              void* d_out, int out_size, void* d_ws, size_t ws_size,
                              hipStream_t stream){
  const float* img1      = (const float*)d_in[0];
  const float* img2      = (const float*)d_in[1];
  const float* pre_w     = (const float*)d_in[2];
  const float* pre_b     = (const float*)d_in[3];
  const float* ln_g      = (const float*)d_in[4];
  const float* ln_b      = (const float*)d_in[5];
  const float* in_w      = (const float*)d_in[6];
  const float* in_b_w    = (const float*)d_in[7];
  const float* conv_w    = (const float*)d_in[8];
  const float* conv_bias = (const float*)d_in[9];
  const float* convb_w   = (const float*)d_in[10];
  const float* convb_bias= (const float*)d_in[11];
  const float* xproj_w   = (const float*)d_in[12];
  const float* xprojb_w  = (const float*)d_in[13];
  const float* dt_w      = (const float*)d_in[14];
  const float* dt_bias   = (const float*)d_in[15];
  const float* dtb_w     = (const float*)d_in[16];
  const float* dtb_bias  = (const float*)d_in[17];
  const float* A_log     = (const float*)d_in[18];
  const float* A_b_log   = (const float*)d_in[19];
  const float* Dp        = (const float*)d_in[20];
  const float* Dp_b      = (const float*)d_in[21];
  const float* norm_w    = (const float*)d_in[22];
  const float* out_w     = (const float*)d_in[23];
  const float* post_w    = (const float*)d_in[24];
  const float* post_b    = (const float*)d_in[25];
  float* ws  = (float*)d_ws;
  float* out = (float*)d_out;

  k_projA<<<1024, 512, 0, stream>>>(img1, img2, pre_w, pre_b, ln_g, ln_b,
                                    in_w, in_b_w, A_log, A_b_log,
                                    conv_w, conv_bias, convb_w, convb_bias,
                                    xproj_w, xprojb_w, dt_w, dt_bias, dtb_w, dtb_bias,
                                    norm_w, out_w, post_w, ws);
  k_scanB<<<64, 256, 0, stream>>>(ws);
  k_scanY<<<512, 1024, 0, stream>>>(Dp, Dp_b, post_b, ws, out);
}

// Round 17
// 58.929 us; speedup vs baseline: 2.7674x; 1.1688x over previous
//
#include <hip/hip_runtime.h>
#include <math.h>

typedef float    f32x4 __attribute__((ext_vector_type(4)));
typedef _Float16 f16x4 __attribute__((ext_vector_type(4)));

#define NCH 32   // scan chunks
#define CLN 32   // chunk length

// workspace float offsets
#define OFF_P     0          // [1024][512] f32
#define OFF_Q     524288     // [1024][512] f32
#define OFF_HIN   1048576    // [1024][512] f32
#define OFF_AN    1572864    // [1024][64]  f32  a1[32],a2[32]
#define OFF_WZ    1638400    // [2][192] f32
#define OFF_VEW   1638784    // [64] f32
#define OFF_AL2   1638848    // [2][512] f32
#define OFF_TILEH 1640448    // half-array base (16B aligned)
// half offsets (units of _Float16) relative to OFF_TILEH base:
#define DTT_H 0              // [1024][64][32]  dt, [d][tt]
#define SXT_H 2097152        // [1024][64][32]  silu(conv(x)), [d][tt]
#define BCT_H 4194304        // [1024][32][16]  B/C, [tt][k]

#define LOG2E 1.4426950408889634f
#define LN2   0.6931471805599453f

__device__ __forceinline__ float fexp2(float x){ return __builtin_amdgcn_exp2f(x); }
__device__ __forceinline__ float flog2(float x){ return __builtin_amdgcn_logf(x); }
__device__ __forceinline__ float frcp (float x){ return __builtin_amdgcn_rcpf(x); }
__device__ __forceinline__ float fsigmoid(float x){ return frcp(1.f + fexp2(-x*LOG2E)); }
__device__ __forceinline__ float fsilu(float x){ return x * fsigmoid(x); }
__device__ __forceinline__ float fsoftplus(float x){
  return fmaxf(x, 0.f) + LN2 * flog2(1.f + fexp2(-fabsf(x)*LOG2E));
}

__device__ __forceinline__ float wave_rsum(float v){
  #pragma unroll
  for (int o = 1; o < 64; o <<= 1) v += __shfl_xor(v, o, 64);
  return v;
}
__device__ __forceinline__ float wave_rmax(float v){
  #pragma unroll
  for (int o = 1; o < 64; o <<= 1) v = fmaxf(v, __shfl_xor(v, o, 64));
  return v;
}

// ---------------- shared scratch for projA ----------------
struct Smem {
  float a1[36], a2[36], a3[36];
  float xpt[20*65];     // padded stride 65
  float dtlr[32*4];
  float sxt[64*37];     // [d][ll] stride 37
  float dtt[64*36];     // [d][ll] stride 36
  float bct[32*16];     // [ll][k]
  float gw[64], gb[64], lnbs[64];
  float W[384];         // this branch's {W1,W2,W3}x128
  float cst[4];         // Av, Bq, Cq
};

__device__ __forceinline__ void consts_ln(float* gw, float* gb, float* lnbs, float* cst, int t,
    const float* pre_w, const float* pre_b, const float* ln_g, const float* ln_b){
  if (t < 64){
    float w = pre_w[t], b = pre_b[t];
    float mw = wave_rsum(w) * (1.f/64.f);
    float mb = wave_rsum(b) * (1.f/64.f);
    float wc = w - mw, bc = b - mb;
    float Av = wave_rsum(wc*wc) * (1.f/64.f);
    float Bq = wave_rsum(wc*bc) * (1.f/64.f);
    float Cq = wave_rsum(bc*bc) * (1.f/64.f);
    gw[t] = wc * ln_g[t];
    gb[t] = bc * ln_g[t];
    lnbs[t] = ln_b[t];
    if (t == 0){ cst[0] = Av; cst[1] = Bq; cst[2] = Cq; }
  }
}

// conv+silu+xproj+dt for one chunk; assumes S.a1/a2/a3 and S.W ready.
__device__ __forceinline__ void proj_body(
    Smem& S, int t,
    const float* __restrict__ cw, const float* __restrict__ cb,
    const float* __restrict__ xpw, const float* __restrict__ dw,
    const float* __restrict__ dbv){
  for (int i = t; i < 20*64; i += 512){
    int k = i >> 6, d = i & 63;
    S.xpt[k*65 + d] = xpw[i];
  }
  __syncthreads();
  {
    int d = t & 63, lq = t >> 6;
    float cw0=cw[d*4], cw1=cw[d*4+1], cw2=cw[d*4+2], cw3=cw[d*4+3];
    float cbd = cb[d];
    float W1d = S.W[d], W2d = S.W[128+d], W3d = S.W[256+d];
    #pragma unroll
    for (int j = 0; j < 4; ++j){
      int ll = lq*4 + j;
      float A1 = cw0*S.a1[ll] + cw1*S.a1[ll+1] + cw2*S.a1[ll+2] + cw3*S.a1[ll+3];
      float A2 = cw0*S.a2[ll] + cw1*S.a2[ll+1] + cw2*S.a2[ll+2] + cw3*S.a2[ll+3];
      float A3 = cw0*S.a3[ll] + cw1*S.a3[ll+1] + cw2*S.a3[ll+2] + cw3*S.a3[ll+3];
      float xc = W1d*A1 + W2d*A2 + W3d*A3 + cbd;
      S.sxt[d*37 + ll] = fsilu(xc);
    }
  }
  __syncthreads();
  {
    int ll = t >> 4, k = t & 15;
    float acc = 0.f;
    #pragma unroll 8
    for (int d = 0; d < 64; ++d) acc += S.xpt[(4+k)*65 + d] * S.sxt[d*37 + ll];
    S.bct[ll*16 + k] = acc;
  }
  if (t < 128){
    int ll = t >> 2, r = t & 3;
    float acc = 0.f;
    #pragma unroll 8
    for (int d = 0; d < 64; ++d) acc += S.xpt[r*65 + d] * S.sxt[d*37 + ll];
    S.dtlr[ll*4 + r] = acc;
  }
  __syncthreads();
  {
    int d = t & 63, lq = t >> 6;
    float w0=dw[d*4], w1=dw[d*4+1], w2=dw[d*4+2], w3=dw[d*4+3];
    float bd = dbv[d];
    #pragma unroll
    for (int j = 0; j < 4; ++j){
      int ll = lq*4 + j;
      float raw = bd + w0*S.dtlr[ll*4] + w1*S.dtlr[ll*4+1]
                     + w2*S.dtlr[ll*4+2] + w3*S.dtlr[ll*4+3];
      S.dtt[d*36 + ll] = fsoftplus(raw);   // [d][tt] layout
    }
  }
  __syncthreads();
}

// ---------------- K1: fused pool + consts + proj + persist fp16 tiles + P,Q ----------------
__global__ void __launch_bounds__(512) k_projA(
    const float* __restrict__ img1, const float* __restrict__ img2,
    const float* pre_w, const float* pre_b, const float* ln_g, const float* ln_b,
    const float* in_w, const float* in_b_w, const float* A_log, const float* A_b_log,
    const float* conv_w, const float* conv_b, const float* convb_w, const float* convb_b,
    const float* xproj_w, const float* xprojb_w,
    const float* dt_w, const float* dt_b, const float* dtb_w, const float* dtb_b,
    const float* norm_w, const float* out_w, const float* post_w,
    float* __restrict__ ws){
  __shared__ __align__(16) Smem S;
  int bi = blockIdx.x;                 // bq*32 + c
  int c = bi & 31, bq = bi >> 5, br = bq >> 4, b = bq & 15;
  int t = threadIdx.x;
  int wv = t >> 6, lane = t & 63;
  // ---- pool: each wave loads its rows (35 rows incl 3-row halo) ----
  const float* img = br ? img2 : img1;
  #pragma unroll
  for (int k = 0; k < 5; ++k){
    int i = wv + k*8;
    if (i < 35){
      bool valid = (c > 0) || (i >= 3);
      if (valid){
        int l = br ? (1026 - c*32 - i) : (c*32 - 3 + i);
        const f32x4* rp = (const f32x4*)(img + ((size_t)(b*1024 + l))*1024) + lane;
        f32x4 q0 = __builtin_nontemporal_load(rp +   0);
        f32x4 q1 = __builtin_nontemporal_load(rp +  64);
        f32x4 q2 = __builtin_nontemporal_load(rp + 128);
        f32x4 q3 = __builtin_nontemporal_load(rp + 192);
        float m = fmaxf(fmaxf(fmaxf(q0.x,q0.y), fmaxf(q0.z,q0.w)),
                        fmaxf(fmaxf(q1.x,q1.y), fmaxf(q1.z,q1.w)));
        m = fmaxf(m, fmaxf(fmaxf(fmaxf(q2.x,q2.y), fmaxf(q2.z,q2.w)),
                           fmaxf(fmaxf(q3.x,q3.y), fmaxf(q3.z,q3.w))));
        m = wave_rmax(m);
        if (lane == 0) S.a1[i] = m;
      } else if (lane == 0) S.a1[i] = 0.f;
    }
  }
  // ---- consts (overlap with load drain) ----
  consts_ln(S.gw, S.gb, S.lnbs, S.cst, t, pre_w, pre_b, ln_g, ln_b);
  __syncthreads();
  if (t < 128){
    const float* iw = br ? in_b_w : in_w;
    float s1 = 0.f, s2 = 0.f, s3 = 0.f;
    #pragma unroll 8
    for (int d = 0; d < 64; ++d){
      float w = iw[t*64 + d];
      s1 += w * S.gw[d]; s2 += w * S.gb[d]; s3 += w * S.lnbs[d];
    }
    S.W[      t] = s1;
    S.W[128 + t] = s2;
    S.W[256 + t] = s3;
  }
  float A2r = -fexp2((br ? A_b_log : A_log)[t] * LOG2E) * LOG2E;
  __syncthreads();
  // ---- convert raw max -> a1/a2/a3 ----
  if (t < 36){
    bool ok = (t < 35) && ((c > 0) || (t >= 3));
    float m = ok ? S.a1[t] : 0.f;
    float Av = S.cst[0], Bq = S.cst[1], Cq = S.cst[2];
    float inv = rsqrtf(m*m*Av + 2.f*m*Bq + Cq + 1e-5f);
    S.a1[t] = ok ? m*inv : 0.f;
    S.a2[t] = ok ? inv   : 0.f;
    S.a3[t] = ok ? 1.f   : 0.f;
  }
  proj_body(S, t,
            br ? convb_w : conv_w,  br ? convb_b : conv_b,
            br ? xprojb_w : xproj_w, br ? dtb_w : dt_w, br ? dtb_b : dt_b);
  // ---- persist tiles (fp16) for scanY; DTT and SXT both [d][tt] ----
  {
    _Float16* th = (_Float16*)(ws + OFF_TILEH);
    int dd = t >> 3, tt0 = (t & 7)*4;
    f32x4 sv; sv.x = S.sxt[dd*37+tt0];   sv.y = S.sxt[dd*37+tt0+1];
              sv.z = S.sxt[dd*37+tt0+2]; sv.w = S.sxt[dd*37+tt0+3];
    *(f16x4*)(th + SXT_H + (size_t)bi*2048 + dd*32 + tt0) =
        __builtin_convertvector(sv, f16x4);
    f32x4 dv = *(const f32x4*)&S.dtt[dd*36 + tt0];
    *(f16x4*)(th + DTT_H + (size_t)bi*2048 + dd*32 + tt0) =
        __builtin_convertvector(dv, f16x4);
    if (t < 128){
      f32x4 bv; bv.x = S.bct[t*4];   bv.y = S.bct[t*4+1];
                bv.z = S.bct[t*4+2]; bv.w = S.bct[t*4+3];
      *(f16x4*)(th + BCT_H + (size_t)bi*512 + t*4) =
          __builtin_convertvector(bv, f16x4);
    }
    if (t < 32){
      ws[OFF_AN + (size_t)bi*64 + t]      = S.a1[t+3];
      ws[OFF_AN + (size_t)bi*64 + 32 + t] = S.a2[t+3];
    }
  }
  // ---- blocks 0 / 512 persist per-branch consts for scanY ----
  if (bi == 0 || bi == 512){
    ws[OFF_AL2 + br*512 + t] = A2r;
    if (t < 64){
      ws[OFF_WZ + br*192 +       t] = S.W[64 + t];
      ws[OFF_WZ + br*192 +  64 + t] = S.W[128 + 64 + t];
      ws[OFF_WZ + br*192 + 128 + t] = S.W[256 + 64 + t];
    }
    if (bi == 0 && t < 64){
      float s = 0.f;
      #pragma unroll 8
      for (int e = 0; e < 64; ++e) s += post_w[e] * out_w[e*64 + t];
      ws[OFF_VEW + t] = s * norm_w[t];
    }
  }
  // ---- per-chunk (P,Q) ----
  int d = wv*8 + (lane >> 3), n = lane & 7;
  float P = 1.f, Q = 0.f;
  #pragma unroll 4
  for (int tt = 0; tt < CLN; ++tt){
    float dtv = S.dtt[d*36 + tt];
    float xv  = S.sxt[d*37 + tt];
    float bv  = S.bct[tt*16 + n];
    float da  = fexp2(dtv * A2r);
    Q = fmaf(da, Q, dtv * bv * xv);
    P *= da;
  }
  ws[OFF_P + (size_t)bi*512 + t] = P;
  ws[OFF_Q + (size_t)bi*512 + t] = Q;
}

// ---------------- K2: combine chunk summaries once -> HIN ----------------
__global__ void __launch_bounds__(256) k_scanB(float* __restrict__ ws){
  int gid = blockIdx.x*256 + threadIdx.x;   // 0..16383
  int bq = gid >> 9, dn = gid & 511;
  size_t base = (size_t)bq*NCH*512 + dn;
  float P[NCH], Q[NCH];
  #pragma unroll
  for (int c = 0; c < NCH; ++c){
    P[c] = ws[OFF_P + base + (size_t)c*512];
    Q[c] = ws[OFF_Q + base + (size_t)c*512];
  }
  float h = 0.f;
  #pragma unroll
  for (int c = 0; c < NCH; ++c){
    ws[OFF_HIN + base + (size_t)c*512] = h;
    h = fmaf(P[c], h, Q[c]);
  }
}

// ---------------- K3: 4-state-per-thread replay + gate + epilogue ----------------
// 256 threads: team = t>>7 (0=fwd,1=bwd); u=t&127; d=u>>1; np=u&1 (n = np*4+j).
// n-reduce = 3 in-register FMAs + ONE shfl_xor(1). LDS ops cut ~6x vs 512-thr version.
__global__ void __launch_bounds__(256) k_scanY(
    const float* Dp, const float* Dp_b, const float* post_b,
    const float* __restrict__ ws, float* __restrict__ out){
  __shared__ __align__(16) struct {
    _Float16 dth[2][64*36];   // [team][d*36+tt] pad36 (bank-spread)
    _Float16 sxh[2][64*36];
    _Float16 bch[2][512];     // [team][tt*16+k]
    float    an [2][64];
    float    ylds[2][CLN*65];
  } C;
  int bi = blockIdx.x;                 // b*32 + oc (output tile)
  int oc = bi & 31, b = bi >> 5;
  int t = threadIdx.x;
  int team = t >> 7, u = t & 127;
  int lane = t & 63;
  int d = u >> 1, np = u & 1;
  int ti = team ? ((b+16)*32 + (31 - oc)) : (b*32 + oc);
  const _Float16* th = (const _Float16*)(ws + OFF_TILEH);
  // ---- per-thread state loads (dn = d*8+n, so f32x4 at u*4) ----
  f32x4 hv  = *(const f32x4*)(ws + OFF_HIN + (size_t)ti*512 + u*4);
  f32x4 a2v = *(const f32x4*)(ws + OFF_AL2 + team*512 + u*4);
  float W1z = ws[OFF_WZ + team*192 +       d];
  float W2z = ws[OFF_WZ + team*192 +  64 + d];
  float W3z = ws[OFF_WZ + team*192 + 128 + d];
  float Dpd = (team ? Dp_b : Dp)[d];
  float ve  = ws[OFF_VEW + lane];
  float pb  = post_b[0];
  // ---- stage tiles into LDS (fp16, padded [d][36]) ----
  #pragma unroll
  for (int k = 0; k < 4; ++k){
    int g = u + k*128;                 // 0..511
    int dd = g >> 3, tt0 = (g & 7)*4;
    f16x4 dh = *(const f16x4*)(th + DTT_H + (size_t)ti*2048 + g*4);
    f16x4 sh = *(const f16x4*)(th + SXT_H + (size_t)ti*2048 + g*4);
    *(f16x4*)&C.dth[team][dd*36 + tt0] = dh;
    *(f16x4*)&C.sxh[team][dd*36 + tt0] = sh;
  }
  *(f16x4*)&C.bch[team][u*4] = *(const f16x4*)(th + BCT_H + (size_t)ti*512 + u*4);
  if (u < 16) *(f32x4*)&C.an[team][u*4] = *(const f32x4*)(ws + OFF_AN + (size_t)ti*64 + u*4);
  __syncthreads();
  // ---- replay: h[4] in registers, per-step 1 shuffle ----
  {
    float h0 = hv.x, h1 = hv.y, h2 = hv.z, h3 = hv.w;
    f32x4 dt4, sx4;
    #pragma unroll
    for (int tt = 0; tt < CLN; ++tt){
      if ((tt & 3) == 0){
        dt4 = __builtin_convertvector(*(const f16x4*)&C.dth[team][d*36 + tt], f32x4);
        sx4 = __builtin_convertvector(*(const f16x4*)&C.sxh[team][d*36 + tt], f32x4);
      }
      float dtv = dt4[tt & 3];
      float xv  = sx4[tt & 3];
      f32x4 bf = __builtin_convertvector(
          *(const f16x4*)&C.bch[team][tt*16 + np*4], f32x4);
      f32x4 cf = __builtin_convertvector(
          *(const f16x4*)&C.bch[team][tt*16 + 8 + np*4], f32x4);
      float dx = dtv * xv;
      h0 = fmaf(fexp2(dtv * a2v.x), h0, dx * bf.x);
      h1 = fmaf(fexp2(dtv * a2v.y), h1, dx * bf.y);
      h2 = fmaf(fexp2(dtv * a2v.z), h2, dx * bf.z);
      h3 = fmaf(fexp2(dtv * a2v.w), h3, dx * bf.w);
      float pv = fmaf(h0, cf.x, fmaf(h1, cf.y, fmaf(h2, cf.z, h3 * cf.w)));
      pv += __shfl_xor(pv, 1, 64);
      if (np == 0){
        float y = pv + Dpd * xv;
        float zv = C.an[team][tt]*W1z + C.an[team][32+tt]*W2z + W3z;
        float g = fsilu(zv);
        int row = team ? (31 - tt) : tt;
        C.ylds[team][row*65 + d] = y * g;
      }
    }
  }
  __syncthreads();
  // ---- epilogue: rmsnorm + collapsed matvec + sigmoid; 4 waves x 8 rows ----
  int wv4 = t >> 6;
  #pragma unroll
  for (int j = 0; j < 8; ++j){
    int row = wv4*8 + j;
    float v = C.ylds[0][row*65 + lane] + C.ylds[1][row*65 + lane];
    float ss = v*v, dp = v*ve;
    #pragma unroll
    for (int o = 1; o < 64; o <<= 1){
      ss += __shfl_xor(ss, o, 64);
      dp += __shfl_xor(dp, o, 64);
    }
    if (lane == 0){
      float rstd = rsqrtf(ss*(1.f/64.f) + 1e-5f);
      out[b*1024 + oc*32 + row] = fsigmoid(dp*rstd + pb);
    }
  }
}

extern "C" void kernel_launch(void* const* d_in, const int* in_sizes, int n_in,
                              void* d_out, int out_size, void* d_ws, size_t ws_size,
                              hipStream_t stream){
  const float* img1      = (const float*)d_in[0];
  const float* img2      = (const float*)d_in[1];
  const float* pre_w     = (const float*)d_in[2];
  const float* pre_b     = (const float*)d_in[3];
  const float* ln_g      = (const float*)d_in[4];
  const float* ln_b      = (const float*)d_in[5];
  const float* in_w      = (const float*)d_in[6];
  const float* in_b_w    = (const float*)d_in[7];
  const float* conv_w    = (const float*)d_in[8];
  const float* conv_bias = (const float*)d_in[9];
  const float* convb_w   = (const float*)d_in[10];
  const float* convb_bias= (const float*)d_in[11];
  const float* xproj_w   = (const float*)d_in[12];
  const float* xprojb_w  = (const float*)d_in[13];
  const float* dt_w      = (const float*)d_in[14];
  const float* dt_bias   = (const float*)d_in[15];
  const float* dtb_w     = (const float*)d_in[16];
  const float* dtb_bias  = (const float*)d_in[17];
  const float* A_log     = (const float*)d_in[18];
  const float* A_b_log   = (const float*)d_in[19];
  const float* Dp        = (const float*)d_in[20];
  const float* Dp_b      = (const float*)d_in[21];
  const float* norm_w    = (const float*)d_in[22];
  const float* out_w     = (const float*)d_in[23];
  const float* post_w    = (const float*)d_in[24];
  const float* post_b    = (const float*)d_in[25];
  float* ws  = (float*)d_ws;
  float* out = (float*)d_out;

  k_projA<<<1024, 512, 0, stream>>>(img1, img2, pre_w, pre_b, ln_g, ln_b,
                                    in_w, in_b_w, A_log, A_b_log,
                                    conv_w, conv_bias, convb_w, convb_bias,
                                    xproj_w, xprojb_w, dt_w, dt_bias, dtb_w, dtb_bias,
                                    norm_w, out_w, post_w, ws);
  k_scanB<<<64, 256, 0, stream>>>(ws);
  k_scanY<<<512, 256, 0, stream>>>(Dp, Dp_b, post_b, ws, out);
}

// Round 18
// 58.626 us; speedup vs baseline: 2.7817x; 1.0052x over previous
//
#include <hip/hip_runtime.h>
#include <math.h>

typedef float    f32x4 __attribute__((ext_vector_type(4)));
typedef _Float16 f16x4 __attribute__((ext_vector_type(4)));

#define NCH 32   // scan chunks
#define CLN 32   // chunk length

// workspace float offsets
#define OFF_P     0          // [1024][512] f32
#define OFF_Q     524288     // [1024][512] f32
#define OFF_HIN   1048576    // [1024][512] f32
#define OFF_AN    1572864    // [1024][64]  f32  a1[32],a2[32]
#define OFF_WZ    1638400    // [2][192] f32
#define OFF_VEW   1638784    // [64] f32
#define OFF_AL2   1638848    // [2][512] f32
#define OFF_TILEH 1640448    // half-array base (16B aligned)
// half offsets (units of _Float16) relative to OFF_TILEH base:
#define DTT_H 0              // [1024][64][32]  dt, [d][tt]
#define SXT_H 2097152        // [1024][64][32]  silu(conv(x)), [d][tt]
#define BCT_H 4194304        // [1024][32][16]  B/C, [tt][k]

#define LOG2E 1.4426950408889634f
#define LN2   0.6931471805599453f

__device__ __forceinline__ float fexp2(float x){ return __builtin_amdgcn_exp2f(x); }
__device__ __forceinline__ float flog2(float x){ return __builtin_amdgcn_logf(x); }
__device__ __forceinline__ float frcp (float x){ return __builtin_amdgcn_rcpf(x); }
__device__ __forceinline__ float fsigmoid(float x){ return frcp(1.f + fexp2(-x*LOG2E)); }
__device__ __forceinline__ float fsilu(float x){ return x * fsigmoid(x); }
__device__ __forceinline__ float fsoftplus(float x){
  return fmaxf(x, 0.f) + LN2 * flog2(1.f + fexp2(-fabsf(x)*LOG2E));
}

__device__ __forceinline__ float wave_rsum(float v){
  #pragma unroll
  for (int o = 1; o < 64; o <<= 1) v += __shfl_xor(v, o, 64);
  return v;
}
__device__ __forceinline__ float wave_rmax(float v){
  #pragma unroll
  for (int o = 1; o < 64; o <<= 1) v = fmaxf(v, __shfl_xor(v, o, 64));
  return v;
}

// ---------------- shared scratch for projA ----------------
struct Smem {
  float a1[36], a2[36], a3[36];
  float xpt[20*65];     // padded stride 65
  float dtlr[32*4];
  float sxt[64*37];     // [d][ll] stride 37
  float dtt[64*36];     // [d][ll] stride 36
  float bct[32*16];     // [ll][k]
  float gw[64], gb[64], lnbs[64];
  float W[384];         // this branch's {W1,W2,W3}x128
  float cst[4];         // Av, Bq, Cq
};

__device__ __forceinline__ void consts_ln(float* gw, float* gb, float* lnbs, float* cst, int t,
    const float* pre_w, const float* pre_b, const float* ln_g, const float* ln_b){
  if (t < 64){
    float w = pre_w[t], b = pre_b[t];
    float mw = wave_rsum(w) * (1.f/64.f);
    float mb = wave_rsum(b) * (1.f/64.f);
    float wc = w - mw, bc = b - mb;
    float Av = wave_rsum(wc*wc) * (1.f/64.f);
    float Bq = wave_rsum(wc*bc) * (1.f/64.f);
    float Cq = wave_rsum(bc*bc) * (1.f/64.f);
    gw[t] = wc * ln_g[t];
    gb[t] = bc * ln_g[t];
    lnbs[t] = ln_b[t];
    if (t == 0){ cst[0] = Av; cst[1] = Bq; cst[2] = Cq; }
  }
}

// conv+silu+xproj+dt for one chunk; assumes S.a1/a2/a3 and S.W ready.
__device__ __forceinline__ void proj_body(
    Smem& S, int t,
    const float* __restrict__ cw, const float* __restrict__ cb,
    const float* __restrict__ xpw, const float* __restrict__ dw,
    const float* __restrict__ dbv){
  for (int i = t; i < 20*64; i += 512){
    int k = i >> 6, d = i & 63;
    S.xpt[k*65 + d] = xpw[i];
  }
  __syncthreads();
  {
    int d = t & 63, lq = t >> 6;
    float cw0=cw[d*4], cw1=cw[d*4+1], cw2=cw[d*4+2], cw3=cw[d*4+3];
    float cbd = cb[d];
    float W1d = S.W[d], W2d = S.W[128+d], W3d = S.W[256+d];
    #pragma unroll
    for (int j = 0; j < 4; ++j){
      int ll = lq*4 + j;
      float A1 = cw0*S.a1[ll] + cw1*S.a1[ll+1] + cw2*S.a1[ll+2] + cw3*S.a1[ll+3];
      float A2 = cw0*S.a2[ll] + cw1*S.a2[ll+1] + cw2*S.a2[ll+2] + cw3*S.a2[ll+3];
      float A3 = cw0*S.a3[ll] + cw1*S.a3[ll+1] + cw2*S.a3[ll+2] + cw3*S.a3[ll+3];
      float xc = W1d*A1 + W2d*A2 + W3d*A3 + cbd;
      S.sxt[d*37 + ll] = fsilu(xc);
    }
  }
  __syncthreads();
  {
    int ll = t >> 4, k = t & 15;
    float acc = 0.f;
    #pragma unroll 8
    for (int d = 0; d < 64; ++d) acc += S.xpt[(4+k)*65 + d] * S.sxt[d*37 + ll];
    S.bct[ll*16 + k] = acc;
  }
  if (t < 128){
    int ll = t >> 2, r = t & 3;
    float acc = 0.f;
    #pragma unroll 8
    for (int d = 0; d < 64; ++d) acc += S.xpt[r*65 + d] * S.sxt[d*37 + ll];
    S.dtlr[ll*4 + r] = acc;
  }
  __syncthreads();
  {
    int d = t & 63, lq = t >> 6;
    float w0=dw[d*4], w1=dw[d*4+1], w2=dw[d*4+2], w3=dw[d*4+3];
    float bd = dbv[d];
    #pragma unroll
    for (int j = 0; j < 4; ++j){
      int ll = lq*4 + j;
      float raw = bd + w0*S.dtlr[ll*4] + w1*S.dtlr[ll*4+1]
                     + w2*S.dtlr[ll*4+2] + w3*S.dtlr[ll*4+3];
      S.dtt[d*36 + ll] = fsoftplus(raw);   // [d][tt] layout
    }
  }
  __syncthreads();
}

// ---------------- K1: fused pool + consts + proj + persist fp16 tiles + P,Q ----------------
__global__ void __launch_bounds__(512) k_projA(
    const float* __restrict__ img1, const float* __restrict__ img2,
    const float* pre_w, const float* pre_b, const float* ln_g, const float* ln_b,
    const float* in_w, const float* in_b_w, const float* A_log, const float* A_b_log,
    const float* conv_w, const float* conv_b, const float* convb_w, const float* convb_b,
    const float* xproj_w, const float* xprojb_w,
    const float* dt_w, const float* dt_b, const float* dtb_w, const float* dtb_b,
    const float* norm_w, const float* out_w, const float* post_w,
    float* __restrict__ ws){
  __shared__ __align__(16) Smem S;
  int bi = blockIdx.x;                 // bq*32 + c
  int c = bi & 31, bq = bi >> 5, br = bq >> 4, b = bq & 15;
  int t = threadIdx.x;
  int wv = t >> 6, lane = t & 63;
  // ---- pool: each wave loads its rows (35 rows incl 3-row halo) ----
  const float* img = br ? img2 : img1;
  #pragma unroll
  for (int k = 0; k < 5; ++k){
    int i = wv + k*8;
    if (i < 35){
      bool valid = (c > 0) || (i >= 3);
      if (valid){
        int l = br ? (1026 - c*32 - i) : (c*32 - 3 + i);
        const f32x4* rp = (const f32x4*)(img + ((size_t)(b*1024 + l))*1024) + lane;
        f32x4 q0 = __builtin_nontemporal_load(rp +   0);
        f32x4 q1 = __builtin_nontemporal_load(rp +  64);
        f32x4 q2 = __builtin_nontemporal_load(rp + 128);
        f32x4 q3 = __builtin_nontemporal_load(rp + 192);
        float m = fmaxf(fmaxf(fmaxf(q0.x,q0.y), fmaxf(q0.z,q0.w)),
                        fmaxf(fmaxf(q1.x,q1.y), fmaxf(q1.z,q1.w)));
        m = fmaxf(m, fmaxf(fmaxf(fmaxf(q2.x,q2.y), fmaxf(q2.z,q2.w)),
                           fmaxf(fmaxf(q3.x,q3.y), fmaxf(q3.z,q3.w))));
        m = wave_rmax(m);
        if (lane == 0) S.a1[i] = m;
      } else if (lane == 0) S.a1[i] = 0.f;
    }
  }
  // ---- consts (overlap with load drain) ----
  consts_ln(S.gw, S.gb, S.lnbs, S.cst, t, pre_w, pre_b, ln_g, ln_b);
  __syncthreads();
  if (t < 128){
    const float* iw = br ? in_b_w : in_w;
    float s1 = 0.f, s2 = 0.f, s3 = 0.f;
    #pragma unroll 8
    for (int d = 0; d < 64; ++d){
      float w = iw[t*64 + d];
      s1 += w * S.gw[d]; s2 += w * S.gb[d]; s3 += w * S.lnbs[d];
    }
    S.W[      t] = s1;
    S.W[128 + t] = s2;
    S.W[256 + t] = s3;
  }
  float A2r = -fexp2((br ? A_b_log : A_log)[t] * LOG2E) * LOG2E;
  __syncthreads();
  // ---- convert raw max -> a1/a2/a3 ----
  if (t < 36){
    bool ok = (t < 35) && ((c > 0) || (t >= 3));
    float m = ok ? S.a1[t] : 0.f;
    float Av = S.cst[0], Bq = S.cst[1], Cq = S.cst[2];
    float inv = rsqrtf(m*m*Av + 2.f*m*Bq + Cq + 1e-5f);
    S.a1[t] = ok ? m*inv : 0.f;
    S.a2[t] = ok ? inv   : 0.f;
    S.a3[t] = ok ? 1.f   : 0.f;
  }
  proj_body(S, t,
            br ? convb_w : conv_w,  br ? convb_b : conv_b,
            br ? xprojb_w : xproj_w, br ? dtb_w : dt_w, br ? dtb_b : dt_b);
  // ---- persist tiles (fp16) for scanY; DTT and SXT both [d][tt] ----
  {
    _Float16* th = (_Float16*)(ws + OFF_TILEH);
    int dd = t >> 3, tt0 = (t & 7)*4;
    f32x4 sv; sv.x = S.sxt[dd*37+tt0];   sv.y = S.sxt[dd*37+tt0+1];
              sv.z = S.sxt[dd*37+tt0+2]; sv.w = S.sxt[dd*37+tt0+3];
    *(f16x4*)(th + SXT_H + (size_t)bi*2048 + dd*32 + tt0) =
        __builtin_convertvector(sv, f16x4);
    f32x4 dv = *(const f32x4*)&S.dtt[dd*36 + tt0];
    *(f16x4*)(th + DTT_H + (size_t)bi*2048 + dd*32 + tt0) =
        __builtin_convertvector(dv, f16x4);
    if (t < 128){
      f32x4 bv; bv.x = S.bct[t*4];   bv.y = S.bct[t*4+1];
                bv.z = S.bct[t*4+2]; bv.w = S.bct[t*4+3];
      *(f16x4*)(th + BCT_H + (size_t)bi*512 + t*4) =
          __builtin_convertvector(bv, f16x4);
    }
    if (t < 32){
      ws[OFF_AN + (size_t)bi*64 + t]      = S.a1[t+3];
      ws[OFF_AN + (size_t)bi*64 + 32 + t] = S.a2[t+3];
    }
  }
  // ---- blocks 0 / 512 persist per-branch consts for scanY ----
  if (bi == 0 || bi == 512){
    ws[OFF_AL2 + br*512 + t] = A2r;
    if (t < 64){
      ws[OFF_WZ + br*192 +       t] = S.W[64 + t];
      ws[OFF_WZ + br*192 +  64 + t] = S.W[128 + 64 + t];
      ws[OFF_WZ + br*192 + 128 + t] = S.W[256 + 64 + t];
    }
    if (bi == 0 && t < 64){
      float s = 0.f;
      #pragma unroll 8
      for (int e = 0; e < 64; ++e) s += post_w[e] * out_w[e*64 + t];
      ws[OFF_VEW + t] = s * norm_w[t];
    }
  }
  // ---- per-chunk (P,Q) ----
  int d = wv*8 + (lane >> 3), n = lane & 7;
  float P = 1.f, Q = 0.f;
  #pragma unroll 4
  for (int tt = 0; tt < CLN; ++tt){
    float dtv = S.dtt[d*36 + tt];
    float xv  = S.sxt[d*37 + tt];
    float bv  = S.bct[tt*16 + n];
    float da  = fexp2(dtv * A2r);
    Q = fmaf(da, Q, dtv * bv * xv);
    P *= da;
  }
  ws[OFF_P + (size_t)bi*512 + t] = P;
  ws[OFF_Q + (size_t)bi*512 + t] = Q;
}

// ---------------- K2: combine chunk summaries once -> HIN (full-depth batch) ----------------
__global__ void __launch_bounds__(64) k_scanB(float* __restrict__ ws){
  int gid = blockIdx.x*64 + threadIdx.x;   // 0..16383
  int bq = gid >> 9, dn = gid & 511;
  size_t base = (size_t)bq*NCH*512 + dn;
  // issue ALL 64 loads before any use: one latency exposure
  float P[NCH], Q[NCH];
  #pragma unroll
  for (int c = 0; c < NCH; ++c) P[c] = ws[OFF_P + base + (size_t)c*512];
  #pragma unroll
  for (int c = 0; c < NCH; ++c) Q[c] = ws[OFF_Q + base + (size_t)c*512];
  float h = 0.f;
  #pragma unroll
  for (int c = 0; c < NCH; ++c){
    ws[OFF_HIN + base + (size_t)c*512] = h;
    h = fmaf(P[c], h, Q[c]);
  }
}

// ---------------- K3: 4-state-per-thread replay + gate + epilogue ----------------
// 256 threads: team = t>>7 (0=fwd,1=bwd); u=t&127; d=u>>1; np=u&1 (n = np*4+j).
__global__ void __launch_bounds__(256) k_scanY(
    const float* Dp, const float* Dp_b, const float* post_b,
    const float* __restrict__ ws, float* __restrict__ out){
  __shared__ __align__(16) struct {
    _Float16 dth[2][64*36];   // [team][d*36+tt] pad36
    _Float16 sxh[2][64*36];
    _Float16 bch[2][512];     // [team][tt*16+k]
    float    an [2][64];
    float    ylds[2][CLN*65];
  } C;
  int bi = blockIdx.x;                 // b*32 + oc (output tile)
  int oc = bi & 31, b = bi >> 5;
  int t = threadIdx.x;
  int team = t >> 7, u = t & 127;
  int lane = t & 63;
  int d = u >> 1, np = u & 1;
  int ti = team ? ((b+16)*32 + (31 - oc)) : (b*32 + oc);
  const _Float16* th = (const _Float16*)(ws + OFF_TILEH);
  // ---- issue ALL global loads back-to-back into registers (max MLP) ----
  f16x4 dh[4], sh[4];
  #pragma unroll
  for (int k = 0; k < 4; ++k){
    int g = u + k*128;
    dh[k] = *(const f16x4*)(th + DTT_H + (size_t)ti*2048 + g*4);
    sh[k] = *(const f16x4*)(th + SXT_H + (size_t)ti*2048 + g*4);
  }
  f16x4 bh = *(const f16x4*)(th + BCT_H + (size_t)ti*512 + u*4);
  f32x4 hv  = *(const f32x4*)(ws + OFF_HIN + (size_t)ti*512 + u*4);
  f32x4 a2v = *(const f32x4*)(ws + OFF_AL2 + team*512 + u*4);
  f32x4 av;
  if (u < 16) av = *(const f32x4*)(ws + OFF_AN + (size_t)ti*64 + u*4);
  float W1z = ws[OFF_WZ + team*192 +       d];
  float W2z = ws[OFF_WZ + team*192 +  64 + d];
  float W3z = ws[OFF_WZ + team*192 + 128 + d];
  float Dpd = (team ? Dp_b : Dp)[d];
  float ve  = ws[OFF_VEW + lane];
  float pb  = post_b[0];
  // ---- stage LDS (all loads already in flight) ----
  #pragma unroll
  for (int k = 0; k < 4; ++k){
    int g = u + k*128;
    int dd = g >> 3, tt0 = (g & 7)*4;
    *(f16x4*)&C.dth[team][dd*36 + tt0] = dh[k];
    *(f16x4*)&C.sxh[team][dd*36 + tt0] = sh[k];
  }
  *(f16x4*)&C.bch[team][u*4] = bh;
  if (u < 16) *(f32x4*)&C.an[team][u*4] = av;
  __syncthreads();
  // ---- replay: h[4] in registers, per-step 1 shuffle ----
  {
    float h0 = hv.x, h1 = hv.y, h2 = hv.z, h3 = hv.w;
    f32x4 dt4, sx4;
    #pragma unroll
    for (int tt = 0; tt < CLN; ++tt){
      if ((tt & 3) == 0){
        dt4 = __builtin_convertvector(*(const f16x4*)&C.dth[team][d*36 + tt], f32x4);
        sx4 = __builtin_convertvector(*(const f16x4*)&C.sxh[team][d*36 + tt], f32x4);
      }
      float dtv = dt4[tt & 3];
      float xv  = sx4[tt & 3];
      f32x4 bf = __builtin_convertvector(
          *(const f16x4*)&C.bch[team][tt*16 + np*4], f32x4);
      f32x4 cf = __builtin_convertvector(
          *(const f16x4*)&C.bch[team][tt*16 + 8 + np*4], f32x4);
      float dx = dtv * xv;
      h0 = fmaf(fexp2(dtv * a2v.x), h0, dx * bf.x);
      h1 = fmaf(fexp2(dtv * a2v.y), h1, dx * bf.y);
      h2 = fmaf(fexp2(dtv * a2v.z), h2, dx * bf.z);
      h3 = fmaf(fexp2(dtv * a2v.w), h3, dx * bf.w);
      float pv = fmaf(h0, cf.x, fmaf(h1, cf.y, fmaf(h2, cf.z, h3 * cf.w)));
      pv += __shfl_xor(pv, 1, 64);
      if (np == 0){
        float y = pv + Dpd * xv;
        float zv = C.an[team][tt]*W1z + C.an[team][32+tt]*W2z + W3z;
        float g = fsilu(zv);
        int row = team ? (31 - tt) : tt;
        C.ylds[team][row*65 + d] = y * g;
      }
    }
  }
  __syncthreads();
  // ---- epilogue: rmsnorm + collapsed matvec + sigmoid; 4 waves x 8 rows ----
  int wv4 = t >> 6;
  #pragma unroll
  for (int j = 0; j < 8; ++j){
    int row = wv4*8 + j;
    float v = C.ylds[0][row*65 + lane] + C.ylds[1][row*65 + lane];
    float ss = v*v, dp = v*ve;
    #pragma unroll
    for (int o = 1; o < 64; o <<= 1){
      ss += __shfl_xor(ss, o, 64);
      dp += __shfl_xor(dp, o, 64);
    }
    if (lane == 0){
      float rstd = rsqrtf(ss*(1.f/64.f) + 1e-5f);
      out[b*1024 + oc*32 + row] = fsigmoid(dp*rstd + pb);
    }
  }
}

extern "C" void kernel_launch(void* const* d_in, const int* in_sizes, int n_in,
                              void* d_out, int out_size, void* d_ws, size_t ws_size,
                              hipStream_t stream){
  const float* img1      = (const float*)d_in[0];
  const float* img2      = (const float*)d_in[1];
  const float* pre_w     = (const float*)d_in[2];
  const float* pre_b     = (const float*)d_in[3];
  const float* ln_g      = (const float*)d_in[4];
  const float* ln_b      = (const float*)d_in[5];
  const float* in_w      = (const float*)d_in[6];
  const float* in_b_w    = (const float*)d_in[7];
  const float* conv_w    = (const float*)d_in[8];
  const float* conv_bias = (const float*)d_in[9];
  const float* convb_w   = (const float*)d_in[10];
  const float* convb_bias= (const float*)d_in[11];
  const float* xproj_w   = (const float*)d_in[12];
  const float* xprojb_w  = (const float*)d_in[13];
  const float* dt_w      = (const float*)d_in[14];
  const float* dt_bias   = (const float*)d_in[15];
  const float* dtb_w     = (const float*)d_in[16];
  const float* dtb_bias  = (const float*)d_in[17];
  const float* A_log     = (const float*)d_in[18];
  const float* A_b_log   = (const float*)d_in[19];
  const float* Dp        = (const float*)d_in[20];
  const float* Dp_b      = (const float*)d_in[21];
  const float* norm_w    = (const float*)d_in[22];
  const float* out_w     = (const float*)d_in[23];
  const float* post_w    = (const float*)d_in[24];
  const float* post_b    = (const float*)d_in[25];
  float* ws  = (float*)d_ws;
  float* out = (float*)d_out;

  k_projA<<<1024, 512, 0, stream>>>(img1, img2, pre_w, pre_b, ln_g, ln_b,
                                    in_w, in_b_w, A_log, A_b_log,
                                    conv_w, conv_bias, convb_w, convb_bias,
                                    xproj_w, xprojb_w, dt_w, dt_bias, dtb_w, dtb_bias,
                                    norm_w, out_w, post_w, ws);
  k_scanB<<<256, 64, 0, stream>>>(ws);
  k_scanY<<<512, 256, 0, stream>>>(Dp, Dp_b, post_b, ws, out);
}